// Round 4
// baseline (6819.405 us; speedup 1.0000x reference)
//
#include <hip/hip_runtime.h>

// ---------------------------------------------------------------------------
// KPlexPool: GCN -> pools -> matrix-free pooled GCN -> MLP head + softmax
// Sizes: N=100000, E=1600000, H=128, M=150000, KC=60000, B=64, C_OUT=10
// ---------------------------------------------------------------------------

#define H 128

__device__ __forceinline__ void atomAddF(float* p, float v) {
    unsafeAtomicAdd(p, v);   // global_atomic_add_f32 on gfx950
}
__device__ __forceinline__ void atomMaxPos(float* p, float v) {
    // valid for non-negative floats (bit pattern order == numeric order)
    atomicMax(reinterpret_cast<int*>(p), __float_as_int(v));
}

// ---- degree accumulation: deg[dst[e]] += w[e] ------------------------------
__global__ void deg_edges(const int* __restrict__ dst, const float* __restrict__ w,
                          float* __restrict__ deg, int E) {
    int e = blockIdx.x * blockDim.x + threadIdx.x;
    if (e < E) atomAddF(&deg[dst[e]], w[e]);
}

// ---- x = rsqrt(x + 1) ------------------------------------------------------
__global__ void rsqrt_inplace(float* __restrict__ p, int n) {
    int i = blockIdx.x * blockDim.x + threadIdx.x;
    if (i < n) p[i] = rsqrtf(p[i] + 1.0f);
}

// ---- GEMM: Out[r][c] (+)= rowscale[r] * sum_k X[r][k] * W[k][c],  K=128 ----
// 64 rows x 128 cols per block, 256 threads, thread = 4 rows x 8 cols.
// W (64KB) staged in LDS; X rows read through L1 (broadcast within lane group).
__global__ __launch_bounds__(256) void gemm128(
    const float* __restrict__ X, const float* __restrict__ W,
    float* __restrict__ Out, int nrows,
    const float* __restrict__ rowscale, int accumulate)
{
    __shared__ float Wl[128 * 128];
    int t = threadIdx.x;
    for (int i = t; i < 4096; i += 256)
        ((float4*)Wl)[i] = ((const float4*)W)[i];
    __syncthreads();

    int cgrp = t & 15;          // 16 col groups of 8 cols
    int rgrp = t >> 4;          // 16 row groups of 4 rows
    long rb = (long)blockIdx.x * 64 + rgrp * 4;
    long nm1 = (long)nrows - 1;
    const float* xr0 = X + (rb + 0 < nm1 ? rb + 0 : nm1) * H;
    const float* xr1 = X + (rb + 1 < nm1 ? rb + 1 : nm1) * H;
    const float* xr2 = X + (rb + 2 < nm1 ? rb + 2 : nm1) * H;
    const float* xr3 = X + (rb + 3 < nm1 ? rb + 3 : nm1) * H;

    float acc[4][8];
#pragma unroll
    for (int i = 0; i < 4; ++i)
#pragma unroll
        for (int j = 0; j < 8; ++j) acc[i][j] = 0.f;

    for (int k = 0; k < 128; ++k) {
        float4 w0 = ((float4*)Wl)[k * 32 + cgrp * 2];
        float4 w1 = ((float4*)Wl)[k * 32 + cgrp * 2 + 1];
        float xv0 = xr0[k], xv1 = xr1[k], xv2 = xr2[k], xv3 = xr3[k];
        acc[0][0] += xv0 * w0.x; acc[0][1] += xv0 * w0.y; acc[0][2] += xv0 * w0.z; acc[0][3] += xv0 * w0.w;
        acc[0][4] += xv0 * w1.x; acc[0][5] += xv0 * w1.y; acc[0][6] += xv0 * w1.z; acc[0][7] += xv0 * w1.w;
        acc[1][0] += xv1 * w0.x; acc[1][1] += xv1 * w0.y; acc[1][2] += xv1 * w0.z; acc[1][3] += xv1 * w0.w;
        acc[1][4] += xv1 * w1.x; acc[1][5] += xv1 * w1.y; acc[1][6] += xv1 * w1.z; acc[1][7] += xv1 * w1.w;
        acc[2][0] += xv2 * w0.x; acc[2][1] += xv2 * w0.y; acc[2][2] += xv2 * w0.z; acc[2][3] += xv2 * w0.w;
        acc[2][4] += xv2 * w1.x; acc[2][5] += xv2 * w1.y; acc[2][6] += xv2 * w1.z; acc[2][7] += xv2 * w1.w;
        acc[3][0] += xv3 * w0.x; acc[3][1] += xv3 * w0.y; acc[3][2] += xv3 * w0.z; acc[3][3] += xv3 * w0.w;
        acc[3][4] += xv3 * w1.x; acc[3][5] += xv3 * w1.y; acc[3][6] += xv3 * w1.z; acc[3][7] += xv3 * w1.w;
    }

#pragma unroll
    for (int i = 0; i < 4; ++i) {
        long gr = rb + i;
        if (gr >= nrows) continue;
        float* o = Out + gr * H + cgrp * 8;
        float4 o0 = make_float4(acc[i][0], acc[i][1], acc[i][2], acc[i][3]);
        float4 o1 = make_float4(acc[i][4], acc[i][5], acc[i][6], acc[i][7]);
        if (accumulate) {
            float4 p0 = ((float4*)o)[0], p1 = ((float4*)o)[1];
            o0.x += p0.x; o0.y += p0.y; o0.z += p0.z; o0.w += p0.w;
            o1.x += p1.x; o1.y += p1.y; o1.z += p1.z; o1.w += p1.w;
        }
        if (rowscale) {
            float s = rowscale[gr];
            o0.x *= s; o0.y *= s; o0.z *= s; o0.w *= s;
            o1.x *= s; o1.y *= s; o1.z *= s; o1.w *= s;
        }
        ((float4*)o)[0] = o0;
        ((float4*)o)[1] = o1;
    }
}

// ---- agg[n][:] = dinv[n]^2 * xw[n][:]  (float4 granularity) ----------------
__global__ void agg_init(const float* __restrict__ xw, const float* __restrict__ dinv,
                         float* __restrict__ agg, long n4) {
    long i = (long)blockIdx.x * blockDim.x + threadIdx.x;
    if (i >= n4) return;
    float d = dinv[i >> 5];
    float dd = d * d;
    float4 v = ((const float4*)xw)[i];
    ((float4*)agg)[i] = make_float4(dd * v.x, dd * v.y, dd * v.z, dd * v.w);
}

// ---- per edge: Acc[dst] += scale * X[src], scale = w (*dinv[s]*dinv[d]) ----
// 32 lanes / edge, float4 per lane
__global__ __launch_bounds__(256) void edge_msg(
    const int* __restrict__ src, const int* __restrict__ dst,
    const float* __restrict__ w, const float* __restrict__ dinv,
    const float* __restrict__ X, float* __restrict__ Acc, int E, int use_dinv)
{
    int e = blockIdx.x * 8 + (threadIdx.x >> 5);
    if (e >= E) return;
    int lane = threadIdx.x & 31;
    int s = src[e], d = dst[e];
    float sc = w[e];
    if (use_dinv) sc *= dinv[s] * dinv[d];
    float4 v = *(const float4*)(X + (long)s * H + lane * 4);
    float* o = Acc + (long)d * H + lane * 4;
    atomAddF(o + 0, sc * v.x);
    atomAddF(o + 1, sc * v.y);
    atomAddF(o + 2, sc * v.z);
    atomAddF(o + 3, sc * v.w);
}

// ---- h = relu(h + bias) ----------------------------------------------------
__global__ void relu_bias(float* __restrict__ h, const float* __restrict__ bias, long n4) {
    long i = (long)blockIdx.x * blockDim.x + threadIdx.x;
    if (i >= n4) return;
    float4 b = ((const float4*)bias)[i & 31];
    float4 v = ((float4*)h)[i];
    v.x = fmaxf(v.x + b.x, 0.f); v.y = fmaxf(v.y + b.y, 0.f);
    v.z = fmaxf(v.z + b.z, 0.f); v.w = fmaxf(v.w + b.w, 0.f);
    ((float4*)h)[i] = v;
}

// ---- per pair: Aadd[idst] += X[isrc]; Amax[idst] = max(.., X[isrc]) --------
__global__ __launch_bounds__(256) void pair_msg(
    const int* __restrict__ isrc, const int* __restrict__ idst,
    const float* __restrict__ X, float* __restrict__ Aadd,
    float* __restrict__ Amax, int M)
{
    int p = blockIdx.x * 8 + (threadIdx.x >> 5);
    if (p >= M) return;
    int lane = threadIdx.x & 31;
    int s = isrc[p], d = idst[p];
    float4 v = *(const float4*)(X + (long)s * H + lane * 4);
    float* o = Aadd + (long)d * H + lane * 4;
    atomAddF(o + 0, v.x); atomAddF(o + 1, v.y);
    atomAddF(o + 2, v.z); atomAddF(o + 3, v.w);
    if (Amax) {
        float* om = Amax + (long)d * H + lane * 4;
        atomMaxPos(om + 0, v.x); atomMaxPos(om + 1, v.y);
        atomMaxPos(om + 2, v.z); atomMaxPos(om + 3, v.w);
    }
}

// ---- sorted-segment pool: sums + maxes of X rows into Z[b*512 + off + j] ---
// seg is sorted; one block handles a contiguous chunk of rows, thread = col.
__global__ __launch_bounds__(128) void seg_pool(
    const float* __restrict__ X, const int* __restrict__ seg,
    float* __restrict__ Z, int n, int sumoff, int maxoff)
{
    int j = threadIdx.x;
    long beg = (long)blockIdx.x * n / gridDim.x;
    long end = (long)(blockIdx.x + 1) * n / gridDim.x;
    if (beg >= end) return;
    int curb = seg[beg];
    float s = 0.f, mx = 0.f;
    for (long i = beg; i < end; ++i) {
        int b = seg[i];
        if (b != curb) {
            atomAddF(&Z[(long)curb * 512 + sumoff + j], s);
            atomMaxPos(&Z[(long)curb * 512 + maxoff + j], mx);
            s = 0.f; mx = 0.f; curb = b;
        }
        float v = X[i * (long)H + j];
        s += v; mx = fmaxf(mx, v);
    }
    atomAddF(&Z[(long)curb * 512 + sumoff + j], s);
    atomMaxPos(&Z[(long)curb * 512 + maxoff + j], mx);
}

// ---- histogram of seg values into cc (float counts) ------------------------
__global__ void hist64(const int* __restrict__ seg, float* __restrict__ cc, int n) {
    __shared__ int hc[128];
    if (threadIdx.x < 128) hc[threadIdx.x] = 0;
    __syncthreads();
    for (int i = blockIdx.x * blockDim.x + threadIdx.x; i < n; i += gridDim.x * blockDim.x)
        atomicAdd(&hc[seg[i]], 1);
    __syncthreads();
    if (threadIdx.x < 128 && hc[threadIdx.x] != 0)
        atomAddF(&cc[threadIdx.x], (float)hc[threadIdx.x]);
}

// ---- scalar pair/edge kernels for degp -------------------------------------
__global__ void zn1_pairs(const int* __restrict__ nodes, float* __restrict__ zn1, int M) {
    int p = blockIdx.x * blockDim.x + threadIdx.x;
    if (p < M) atomAddF(&zn1[nodes[p]], 1.0f);
}
__global__ void ye1_edges(const int* __restrict__ src, const int* __restrict__ dst,
                          const float* __restrict__ w, const float* __restrict__ zn1,
                          float* __restrict__ ye1, int E) {
    int e = blockIdx.x * blockDim.x + threadIdx.x;
    if (e < E) atomAddF(&ye1[dst[e]], w[e] * zn1[src[e]]);
}
__global__ void degp_pairs(const int* __restrict__ nodes, const int* __restrict__ clus,
                           const float* __restrict__ ye1, float* __restrict__ degp, int M) {
    int p = blockIdx.x * blockDim.x + threadIdx.x;
    if (p < M) atomAddF(&degp[clus[p]], ye1[nodes[p]]);
}

// ---- hp = relu(dinvp[r] * (ap + xws) + b_blk), in place over ap ------------
__global__ void hp_kernel(float* __restrict__ ap, const float* __restrict__ xws,
                          const float* __restrict__ dinvp, const float* __restrict__ bias,
                          long n4) {
    long i = (long)blockIdx.x * blockDim.x + threadIdx.x;
    if (i >= n4) return;
    float d = dinvp[i >> 5];
    float4 b = ((const float4*)bias)[i & 31];
    float4 a = ((float4*)ap)[i];
    float4 xv = ((const float4*)xws)[i];
    a.x = fmaxf(d * (a.x + xv.x) + b.x, 0.f);
    a.y = fmaxf(d * (a.y + xv.y) + b.y, 0.f);
    a.z = fmaxf(d * (a.z + xv.z) + b.z, 0.f);
    a.w = fmaxf(d * (a.w + xv.w) + b.w, 0.f);
    ((float4*)ap)[i] = a;
}

// ---- head: BN -> relu(z@W1+b1) -> z1@W2+b2 -> softmax ----------------------
__global__ __launch_bounds__(128) void head_kernel(
    const float* __restrict__ z, const float* __restrict__ cc,
    const float* __restrict__ gamma, const float* __restrict__ beta,
    const float* __restrict__ bmean, const float* __restrict__ bvar,
    const float* __restrict__ W1, const float* __restrict__ b1,
    const float* __restrict__ W2, const float* __restrict__ b2,
    float* __restrict__ out)
{
    __shared__ float zb[512];
    __shared__ float z1[128];
    __shared__ float lg[10];
    __shared__ float red[2];
    int b = blockIdx.x, t = threadIdx.x;
    float ccb = cc[b];
    for (int k = t; k < 512; k += 128) {
        float v = z[(long)b * 512 + k];
        if (k >= 256 && k < 384) v /= ccb;                 // mean pool
        v = (v - bmean[k]) * rsqrtf(bvar[k] + 1e-5f) * gamma[k] + beta[k];
        zb[k] = v;
    }
    __syncthreads();
    float acc = b1[t];
    for (int k = 0; k < 512; ++k) acc += zb[k] * W1[k * 128 + t];
    z1[t] = fmaxf(acc, 0.f);
    __syncthreads();
    if (t < 10) {
        float a = b2[t];
        for (int k = 0; k < 128; ++k) a += z1[k] * W2[k * 10 + t];
        lg[t] = a;
    }
    __syncthreads();
    if (t == 0) {
        float m = lg[0];
        for (int i = 1; i < 10; ++i) m = fmaxf(m, lg[i]);
        float s = 0.f;
        for (int i = 0; i < 10; ++i) s += expf(lg[i] - m);
        red[0] = m; red[1] = s;
    }
    __syncthreads();
    if (t < 10) out[(long)b * 10 + t] = expf(lg[t] - red[0]) / red[1];
}

// ---------------------------------------------------------------------------
extern "C" void kernel_launch(void* const* d_in, const int* in_sizes, int n_in,
                              void* d_out, int out_size, void* d_ws, size_t ws_size,
                              hipStream_t stream)
{
    const float* x      = (const float*)d_in[0];
    const int*   ei     = (const int*)  d_in[1];
    const float* wts    = (const float*)d_in[2];
    const int*   batch  = (const int*)  d_in[3];
    const int*   cnodes = (const int*)  d_in[4];
    const int*   cclus  = (const int*)  d_in[5];
    const int*   cbatch = (const int*)  d_in[6];
    const float* Win    = (const float*)d_in[7];
    const float* bin    = (const float*)d_in[8];
    const float* Wblk   = (const float*)d_in[9];
    const float* bblk   = (const float*)d_in[10];
    const float* gma    = (const float*)d_in[11];
    const float* bta    = (const float*)d_in[12];
    const float* bmean  = (const float*)d_in[13];
    const float* bvar   = (const float*)d_in[14];
    const float* W1     = (const float*)d_in[15];
    const float* b1     = (const float*)d_in[16];
    const float* W2     = (const float*)d_in[17];
    const float* b2     = (const float*)d_in[18];
    float* out = (float*)d_out;

    const int N  = in_sizes[0] / H;
    const int E  = in_sizes[1] / 2;
    const int M  = in_sizes[4];
    const int KC = in_sizes[6];
    const int Bq = out_size / 10;

    const int* src = ei;
    const int* dst = ei + E;

    float* ws = (float*)d_ws;
    const long NH = (long)N * H;
    const long KH = (long)KC * H;
    float* A    = ws;            // xw, later zn            [NH]
    float* Bb   = A + NH;        // agg/h, later ye         [NH]
    float* C    = Bb + NH;       // x_add, later ap/hp      [KH]
    float* D    = C + KH;        // x_max                   [KH]
    float* Ebuf = D + KH;        // xw_p / xws              [KH]
    float* deg  = Ebuf + KH;     // deg -> dinv             [N]
    float* zn1  = deg + N;       //                         [N]
    float* ye1  = zn1 + N;       //                         [N]
    float* degp = ye1 + N;       // degp -> dinvp           [KC]
    float* z    = degp + KC;     // pooled features         [Bq*512]
    float* cc   = z + (long)Bq * 512;  // cluster counts    [Bq]

    // zero small accumulators (deg, zn1, ye1, degp, z, cc are contiguous)
    hipMemsetAsync(deg, 0, (3L * N + KC + (long)Bq * 512 + Bq) * sizeof(float), stream);

    // 1. weighted degree + dinv
    deg_edges<<<(E + 255) / 256, 256, 0, stream>>>(dst, wts, deg, E);
    rsqrt_inplace<<<(N + 255) / 256, 256, 0, stream>>>(deg, N);

    // 2. xw = x @ W_in
    gemm128<<<(N + 63) / 64, 256, 0, stream>>>(x, Win, A, N, nullptr, 0);

    // 3. conv_in: agg = dinv^2*xw + sum_msgs; h = relu(agg + b_in)
    agg_init<<<(int)((NH / 4 + 255) / 256), 256, 0, stream>>>(A, deg, Bb, NH / 4);
    edge_msg<<<(E + 7) / 8, 256, 0, stream>>>(src, dst, wts, deg, A, Bb, E, 1);
    relu_bias<<<(int)((NH / 4 + 255) / 256), 256, 0, stream>>>(Bb, bin, NH / 4);

    // 4. global pools of h + cover pools
    hipMemsetAsync(C, 0, 2 * KH * sizeof(float), stream);   // x_add, x_max
    pair_msg<<<(M + 7) / 8, 256, 0, stream>>>(cnodes, cclus, Bb, C, D, M);
    seg_pool<<<1024, 128, 0, stream>>>(Bb, batch, z, N, 0, 128);
    hist64<<<256, 256, 0, stream>>>(cbatch, cc, KC);

    // 5. degp = aprime(ones) + 1 -> dinvp
    zn1_pairs<<<(M + 255) / 256, 256, 0, stream>>>(cnodes, zn1, M);
    ye1_edges<<<(E + 255) / 256, 256, 0, stream>>>(src, dst, wts, zn1, ye1, E);
    degp_pairs<<<(M + 255) / 256, 256, 0, stream>>>(cnodes, cclus, ye1, degp, M);
    rsqrt_inplace<<<(KC + 255) / 256, 256, 0, stream>>>(degp, KC);

    // 6. xws = dinvp * (x_add @ Wblk_top + x_max @ Wblk_bot)
    gemm128<<<(KC + 63) / 64, 256, 0, stream>>>(C, Wblk, Ebuf, KC, nullptr, 0);
    gemm128<<<(KC + 63) / 64, 256, 0, stream>>>(D, Wblk + 128 * 128, Ebuf, KC, degp, 1);

    // 7. aprime(xws): zn (A) -> ye (Bb) -> ap (C)
    hipMemsetAsync(A, 0, NH * sizeof(float), stream);
    pair_msg<<<(M + 7) / 8, 256, 0, stream>>>(cclus, cnodes, Ebuf, A, nullptr, M);
    hipMemsetAsync(Bb, 0, NH * sizeof(float), stream);
    edge_msg<<<(E + 7) / 8, 256, 0, stream>>>(src, dst, wts, nullptr, A, Bb, E, 0);
    hipMemsetAsync(C, 0, KH * sizeof(float), stream);
    pair_msg<<<(M + 7) / 8, 256, 0, stream>>>(cnodes, cclus, Bb, C, nullptr, M);

    // 8. hp = relu(dinvp * (ap + xws) + b_blk)   (in place over C)
    hp_kernel<<<(int)((KH / 4 + 255) / 256), 256, 0, stream>>>(C, Ebuf, degp, bblk, KH / 4);

    // 9. cluster pools of hp (sum -> mean later, max)
    seg_pool<<<512, 128, 0, stream>>>(C, cbatch, z, KC, 256, 384);

    // 10. head: BN -> MLP -> softmax
    head_kernel<<<Bq, 128, 0, stream>>>(z, cc, gma, bta, bmean, bvar, W1, b1, W2, b2, out);
}

// Round 5
// 862.582 us; speedup vs baseline: 7.9058x; 7.9058x over previous
//
#include <hip/hip_runtime.h>

// ---------------------------------------------------------------------------
// KPlexPool: GCN -> pools -> matrix-free pooled GCN -> MLP head + softmax
// Sizes: N=100000, E=1600000, H=128, M=150000, KC=60000, B=64, C_OUT=10
// Round 4: scatter-atomics -> device-built CSR gathers (atomic wall was 77G/s,
// VALUBusy 1.3%, WRITE_SIZE 4x payload). All vector scatters eliminated.
// ---------------------------------------------------------------------------

#define H 128

__device__ __forceinline__ void atomAddF(float* p, float v) {
    unsafeAtomicAdd(p, v);   // global_atomic_add_f32 on gfx950
}
__device__ __forceinline__ void atomMaxPos(float* p, float v) {
    // valid for non-negative floats (bit pattern order == numeric order)
    atomicMax(reinterpret_cast<int*>(p), __float_as_int(v));
}

// ========================= CSR build =======================================
__global__ void count_kernel(const int* __restrict__ key, int* __restrict__ cnt, int n) {
    int i = blockIdx.x * blockDim.x + threadIdx.x;
    if (i < n) atomicAdd(&cnt[key[i]], 1);
}

// exclusive scan of c[0..m) in place, 1024 elems/block
__global__ __launch_bounds__(256) void scan_partial(const int* __restrict__ c,
                                                    int* __restrict__ part, int m) {
    __shared__ int red[4];
    int base = blockIdx.x * 1024, t = threadIdx.x;
    int s = 0;
    for (int j = t; j < 1024; j += 256) { int i = base + j; if (i < m) s += c[i]; }
    for (int o = 32; o; o >>= 1) s += __shfl_down(s, o, 64);
    if ((t & 63) == 0) red[t >> 6] = s;
    __syncthreads();
    if (t == 0) part[blockIdx.x] = red[0] + red[1] + red[2] + red[3];
}
__global__ void scan_spine(int* part, int G) {
    if (threadIdx.x == 0) {
        int acc = 0;
        for (int i = 0; i < G; ++i) { int v = part[i]; part[i] = acc; acc += v; }
    }
}
__global__ __launch_bounds__(256) void scan_apply(int* __restrict__ c,
                                                  const int* __restrict__ part, int m) {
    __shared__ int wsum[4];
    int base = blockIdx.x * 1024, t = threadIdx.x;
    int i0 = base + t * 4;
    int v0 = 0, v1 = 0, v2 = 0, v3 = 0;
    if (i0     < m) v0 = c[i0];
    if (i0 + 1 < m) v1 = c[i0 + 1];
    if (i0 + 2 < m) v2 = c[i0 + 2];
    if (i0 + 3 < m) v3 = c[i0 + 3];
    int ts = v0 + v1 + v2 + v3;
    int lane = t & 63, w = t >> 6;
    int sc = ts;
    for (int o = 1; o < 64; o <<= 1) { int u = __shfl_up(sc, o, 64); if (lane >= o) sc += u; }
    if (lane == 63) wsum[w] = sc;
    __syncthreads();
    int off = part[blockIdx.x];
    for (int k = 0; k < w; ++k) off += wsum[k];
    int ex = off + sc - ts;
    if (i0     < m) c[i0]     = ex;
    if (i0 + 1 < m) c[i0 + 1] = ex + v0;
    if (i0 + 2 < m) c[i0 + 2] = ex + v0 + v1;
    if (i0 + 3 < m) c[i0 + 3] = ex + v0 + v1 + v2;
}

// fill: after this, offs[i] = end of bucket i; row i = [i?offs[i-1]:0, offs[i])
__global__ void fill_edges(const int* __restrict__ src, const int* __restrict__ dst,
                           const float* __restrict__ w, int* __restrict__ offs,
                           int* __restrict__ pack, int E) {
    int e = blockIdx.x * blockDim.x + threadIdx.x;
    if (e >= E) return;
    int pos = atomicAdd(&offs[dst[e]], 1);
    ((int2*)pack)[pos] = make_int2(src[e], __float_as_int(w[e]));
}
__global__ void fill_pairs(const int* __restrict__ key, const int* __restrict__ val,
                           int* __restrict__ offs, int* __restrict__ slots, int M) {
    int p = blockIdx.x * blockDim.x + threadIdx.x;
    if (p >= M) return;
    int pos = atomicAdd(&offs[key[p]], 1);
    slots[pos] = val[p];
}

// ========================= scalar CSR reductions ===========================
// dinv[n] = rsqrt(sum_e w + 1);  ye1[n] = sum_e w * paircount[src]
__global__ void node_scalars(const int* __restrict__ eoffs, const int* __restrict__ epack,
                             const int* __restrict__ qoffs,
                             float* __restrict__ dinv, float* __restrict__ ye1, int N) {
    int n = blockIdx.x * blockDim.x + threadIdx.x;
    if (n >= N) return;
    int b = n ? eoffs[n - 1] : 0, e = eoffs[n];
    float dg = 0.f, y = 0.f;
    for (int i = b; i < e; ++i) {
        int2 pk = ((const int2*)epack)[i];
        float w = __int_as_float(pk.y);
        dg += w;
        int zc = qoffs[pk.x] - (pk.x ? qoffs[pk.x - 1] : 0);
        y += w * (float)zc;
    }
    dinv[n] = rsqrtf(dg + 1.0f);
    ye1[n] = y;
}
// dinvp[c] = rsqrt(sum_{p in cluster c} ye1[node_p] + 1)
__global__ void cluster_dinvp(const int* __restrict__ poffs, const int* __restrict__ pslots,
                              const float* __restrict__ ye1, float* __restrict__ dinvp, int KC) {
    int c = blockIdx.x * blockDim.x + threadIdx.x;
    if (c >= KC) return;
    int b = c ? poffs[c - 1] : 0, e = poffs[c];
    float s = 0.f;
    for (int i = b; i < e; ++i) s += ye1[pslots[i]];
    dinvp[c] = rsqrtf(s + 1.0f);
}

// ========================= GEMM K=128 ======================================
// 64 rows x 128 cols per block, 256 threads, thread = 4 rows x 8 cols.
// NOTE: no __restrict__ on X/Out -- called in-place (X==Out); the
// __syncthreads() before writeback makes intra-block row sharing safe.
__global__ __launch_bounds__(256) void gemm128(
    const float* X, const float* __restrict__ W,
    float* Out, int nrows,
    const float* __restrict__ rowscale, int accumulate)
{
    __shared__ float Wl[128 * 128];
    int t = threadIdx.x;
    for (int i = t; i < 4096; i += 256)
        ((float4*)Wl)[i] = ((const float4*)W)[i];
    __syncthreads();

    int cgrp = t & 15;
    int rgrp = t >> 4;
    long rb = (long)blockIdx.x * 64 + rgrp * 4;
    long nm1 = (long)nrows - 1;
    const float* xr0 = X + (rb + 0 < nm1 ? rb + 0 : nm1) * H;
    const float* xr1 = X + (rb + 1 < nm1 ? rb + 1 : nm1) * H;
    const float* xr2 = X + (rb + 2 < nm1 ? rb + 2 : nm1) * H;
    const float* xr3 = X + (rb + 3 < nm1 ? rb + 3 : nm1) * H;

    float acc[4][8];
#pragma unroll
    for (int i = 0; i < 4; ++i)
#pragma unroll
        for (int j = 0; j < 8; ++j) acc[i][j] = 0.f;

    for (int k = 0; k < 128; ++k) {
        float4 w0 = ((float4*)Wl)[k * 32 + cgrp * 2];
        float4 w1 = ((float4*)Wl)[k * 32 + cgrp * 2 + 1];
        float xv0 = xr0[k], xv1 = xr1[k], xv2 = xr2[k], xv3 = xr3[k];
        acc[0][0] += xv0 * w0.x; acc[0][1] += xv0 * w0.y; acc[0][2] += xv0 * w0.z; acc[0][3] += xv0 * w0.w;
        acc[0][4] += xv0 * w1.x; acc[0][5] += xv0 * w1.y; acc[0][6] += xv0 * w1.z; acc[0][7] += xv0 * w1.w;
        acc[1][0] += xv1 * w0.x; acc[1][1] += xv1 * w0.y; acc[1][2] += xv1 * w0.z; acc[1][3] += xv1 * w0.w;
        acc[1][4] += xv1 * w1.x; acc[1][5] += xv1 * w1.y; acc[1][6] += xv1 * w1.z; acc[1][7] += xv1 * w1.w;
        acc[2][0] += xv2 * w0.x; acc[2][1] += xv2 * w0.y; acc[2][2] += xv2 * w0.z; acc[2][3] += xv2 * w0.w;
        acc[2][4] += xv2 * w1.x; acc[2][5] += xv2 * w1.y; acc[2][6] += xv2 * w1.z; acc[2][7] += xv2 * w1.w;
        acc[3][0] += xv3 * w0.x; acc[3][1] += xv3 * w0.y; acc[3][2] += xv3 * w0.z; acc[3][3] += xv3 * w0.w;
        acc[3][4] += xv3 * w1.x; acc[3][5] += xv3 * w1.y; acc[3][6] += xv3 * w1.z; acc[3][7] += xv3 * w1.w;
    }

    __syncthreads();   // in-place safety: all reads of X complete before any write

#pragma unroll
    for (int i = 0; i < 4; ++i) {
        long gr = rb + i;
        if (gr >= nrows) continue;
        float* o = Out + gr * H + cgrp * 8;
        float4 o0 = make_float4(acc[i][0], acc[i][1], acc[i][2], acc[i][3]);
        float4 o1 = make_float4(acc[i][4], acc[i][5], acc[i][6], acc[i][7]);
        if (accumulate) {
            float4 p0 = ((float4*)o)[0], p1 = ((float4*)o)[1];
            o0.x += p0.x; o0.y += p0.y; o0.z += p0.z; o0.w += p0.w;
            o1.x += p1.x; o1.y += p1.y; o1.z += p1.z; o1.w += p1.w;
        }
        if (rowscale) {
            float s = rowscale[gr];
            o0.x *= s; o0.y *= s; o0.z *= s; o0.w *= s;
            o1.x *= s; o1.y *= s; o1.z *= s; o1.w *= s;
        }
        ((float4*)o)[0] = o0;
        ((float4*)o)[1] = o1;
    }
}

// ========================= vector CSR gathers ==============================
// GCN pass 1, fully fused: h[n] = relu(dinv_n*(sum w*dinv_s*xw[s] + dinv_n*xw[n]) + b)
// one wave (64 lanes) per node, float2 per lane; edge scalars batch-loaded + shfl
__global__ __launch_bounds__(256) void gcn1_gather(
    const int* __restrict__ eoffs, const int* __restrict__ epack,
    const float* __restrict__ dinv, const float* __restrict__ xw,
    const float* __restrict__ bin, float* __restrict__ h, int N)
{
    int n = blockIdx.x * 4 + (threadIdx.x >> 6);
    if (n >= N) return;
    int lane = threadIdx.x & 63;
    int b = n ? eoffs[n - 1] : 0, e = eoffs[n];
    const float2* X2 = (const float2*)xw;
    float2 acc = make_float2(0.f, 0.f);
    for (int i = b; i < e; i += 64) {
        int cnt = min(64, e - i);
        int s_l = 0; float sc_l = 0.f;
        if (lane < cnt) {
            int2 pk = ((const int2*)epack)[i + lane];
            s_l = pk.x;
            sc_l = __int_as_float(pk.y) * dinv[pk.x];
        }
        for (int j = 0; j < cnt; ++j) {
            int s = __shfl(s_l, j, 64);
            float sc = __shfl(sc_l, j, 64);
            float2 v = X2[(long)s * 64 + lane];
            acc.x += sc * v.x; acc.y += sc * v.y;
        }
    }
    float dd = dinv[n];
    float2 self = X2[(long)n * 64 + lane];
    float2 bb = ((const float2*)bin)[lane];
    float2 o;
    o.x = fmaxf(dd * (acc.x + dd * self.x) + bb.x, 0.f);
    o.y = fmaxf(dd * (acc.y + dd * self.y) + bb.y, 0.f);
    ((float2*)h)[(long)n * 64 + lane] = o;
}

// plain edge gather: Out[n] = sum_e w * X[src]
__global__ __launch_bounds__(256) void edge_gather_plain(
    const int* __restrict__ eoffs, const int* __restrict__ epack,
    const float* __restrict__ X, float* __restrict__ Out, int N)
{
    int n = blockIdx.x * 4 + (threadIdx.x >> 6);
    if (n >= N) return;
    int lane = threadIdx.x & 63;
    int b = n ? eoffs[n - 1] : 0, e = eoffs[n];
    const float2* X2 = (const float2*)X;
    float2 acc = make_float2(0.f, 0.f);
    for (int i = b; i < e; i += 64) {
        int cnt = min(64, e - i);
        int s_l = 0; float sc_l = 0.f;
        if (lane < cnt) {
            int2 pk = ((const int2*)epack)[i + lane];
            s_l = pk.x; sc_l = __int_as_float(pk.y);
        }
        for (int j = 0; j < cnt; ++j) {
            int s = __shfl(s_l, j, 64);
            float sc = __shfl(sc_l, j, 64);
            float2 v = X2[(long)s * 64 + lane];
            acc.x += sc * v.x; acc.y += sc * v.y;
        }
    }
    ((float2*)Out)[(long)n * 64 + lane] = acc;
}

// cover pool: x_add[c] = sum h[node], x_max[c] = max h[node]  (h >= 0)
__global__ __launch_bounds__(256) void cover_pool(
    const int* __restrict__ poffs, const int* __restrict__ pslots,
    const float* __restrict__ h, float* __restrict__ xadd,
    float* __restrict__ xmax, int KC)
{
    int c = blockIdx.x * 4 + (threadIdx.x >> 6);
    if (c >= KC) return;
    int lane = threadIdx.x & 63;
    int b = c ? poffs[c - 1] : 0, e = poffs[c];
    const float2* H2 = (const float2*)h;
    float2 s = make_float2(0.f, 0.f), m = make_float2(0.f, 0.f);
    for (int i = b; i < e; ++i) {
        int nd = pslots[i];
        float2 v = H2[(long)nd * 64 + lane];
        s.x += v.x; s.y += v.y;
        m.x = fmaxf(m.x, v.x); m.y = fmaxf(m.y, v.y);
    }
    ((float2*)xadd)[(long)c * 64 + lane] = s;
    ((float2*)xmax)[(long)c * 64 + lane] = m;
}

// zn[n] = sum_{p at node n} xws[cluster_p]
__global__ __launch_bounds__(256) void zn_gather(
    const int* __restrict__ qoffs, const int* __restrict__ qslots,
    const float* __restrict__ xws, float* __restrict__ zn, int N)
{
    int n = blockIdx.x * 4 + (threadIdx.x >> 6);
    if (n >= N) return;
    int lane = threadIdx.x & 63;
    int b = n ? qoffs[n - 1] : 0, e = qoffs[n];
    const float2* X2 = (const float2*)xws;
    float2 a = make_float2(0.f, 0.f);
    for (int i = b; i < e; ++i) {
        int c = qslots[i];
        float2 v = X2[(long)c * 64 + lane];
        a.x += v.x; a.y += v.y;
    }
    ((float2*)zn)[(long)n * 64 + lane] = a;
}

// hp[c] = relu(dinvp_c * (sum_{p in c} ye[node_p] + xws[c]) + b_blk)
__global__ __launch_bounds__(256) void aphp_gather(
    const int* __restrict__ poffs, const int* __restrict__ pslots,
    const float* __restrict__ ye, const float* __restrict__ xws,
    const float* __restrict__ dinvp, const float* __restrict__ bblk,
    float* __restrict__ hp, int KC)
{
    int c = blockIdx.x * 4 + (threadIdx.x >> 6);
    if (c >= KC) return;
    int lane = threadIdx.x & 63;
    int b = c ? poffs[c - 1] : 0, e = poffs[c];
    const float2* Y2 = (const float2*)ye;
    float2 a = make_float2(0.f, 0.f);
    for (int i = b; i < e; ++i) {
        int nd = pslots[i];
        float2 v = Y2[(long)nd * 64 + lane];
        a.x += v.x; a.y += v.y;
    }
    float d = dinvp[c];
    float2 xv = ((const float2*)xws)[(long)c * 64 + lane];
    float2 bb = ((const float2*)bblk)[lane];
    float2 o;
    o.x = fmaxf(d * (a.x + xv.x) + bb.x, 0.f);
    o.y = fmaxf(d * (a.y + xv.y) + bb.y, 0.f);
    ((float2*)hp)[(long)c * 64 + lane] = o;
}

// ========================= batch pools + head ==============================
__global__ __launch_bounds__(128) void seg_pool(
    const float* __restrict__ X, const int* __restrict__ seg,
    float* __restrict__ Z, int n, int sumoff, int maxoff)
{
    int j = threadIdx.x;
    long beg = (long)blockIdx.x * n / gridDim.x;
    long end = (long)(blockIdx.x + 1) * n / gridDim.x;
    if (beg >= end) return;
    int curb = seg[beg];
    float s = 0.f, mx = 0.f;
    for (long i = beg; i < end; ++i) {
        int b = seg[i];
        if (b != curb) {
            atomAddF(&Z[(long)curb * 512 + sumoff + j], s);
            atomMaxPos(&Z[(long)curb * 512 + maxoff + j], mx);
            s = 0.f; mx = 0.f; curb = b;
        }
        float v = X[i * (long)H + j];
        s += v; mx = fmaxf(mx, v);
    }
    atomAddF(&Z[(long)curb * 512 + sumoff + j], s);
    atomMaxPos(&Z[(long)curb * 512 + maxoff + j], mx);
}

__global__ void hist64(const int* __restrict__ seg, float* __restrict__ cc, int n) {
    __shared__ int hc[128];
    if (threadIdx.x < 128) hc[threadIdx.x] = 0;
    __syncthreads();
    for (int i = blockIdx.x * blockDim.x + threadIdx.x; i < n; i += gridDim.x * blockDim.x)
        atomicAdd(&hc[seg[i]], 1);
    __syncthreads();
    if (threadIdx.x < 128 && hc[threadIdx.x] != 0)
        atomAddF(&cc[threadIdx.x], (float)hc[threadIdx.x]);
}

__global__ __launch_bounds__(128) void head_kernel(
    const float* __restrict__ z, const float* __restrict__ cc,
    const float* __restrict__ gamma, const float* __restrict__ beta,
    const float* __restrict__ bmean, const float* __restrict__ bvar,
    const float* __restrict__ W1, const float* __restrict__ b1,
    const float* __restrict__ W2, const float* __restrict__ b2,
    float* __restrict__ out)
{
    __shared__ float zb[512];
    __shared__ float z1[128];
    __shared__ float lg[10];
    __shared__ float red[2];
    int b = blockIdx.x, t = threadIdx.x;
    float ccb = cc[b];
    for (int k = t; k < 512; k += 128) {
        float v = z[(long)b * 512 + k];
        if (k >= 256 && k < 384) v /= ccb;
        v = (v - bmean[k]) * rsqrtf(bvar[k] + 1e-5f) * gamma[k] + beta[k];
        zb[k] = v;
    }
    __syncthreads();
    float acc = b1[t];
    for (int k = 0; k < 512; ++k) acc += zb[k] * W1[k * 128 + t];
    z1[t] = fmaxf(acc, 0.f);
    __syncthreads();
    if (t < 10) {
        float a = b2[t];
        for (int k = 0; k < 128; ++k) a += z1[k] * W2[k * 10 + t];
        lg[t] = a;
    }
    __syncthreads();
    if (t == 0) {
        float m = lg[0];
        for (int i = 1; i < 10; ++i) m = fmaxf(m, lg[i]);
        float s = 0.f;
        for (int i = 0; i < 10; ++i) s += expf(lg[i] - m);
        red[0] = m; red[1] = s;
    }
    __syncthreads();
    if (t < 10) out[(long)b * 10 + t] = expf(lg[t] - red[0]) / red[1];
}

// ---------------------------------------------------------------------------
static void scan_ex(int* buf, int m, int* part, hipStream_t s) {
    int G = (m + 1023) / 1024;
    scan_partial<<<G, 256, 0, s>>>(buf, part, m);
    scan_spine<<<1, 64, 0, s>>>(part, G);
    scan_apply<<<G, 256, 0, s>>>(buf, part, m);
}

extern "C" void kernel_launch(void* const* d_in, const int* in_sizes, int n_in,
                              void* d_out, int out_size, void* d_ws, size_t ws_size,
                              hipStream_t stream)
{
    const float* x      = (const float*)d_in[0];
    const int*   ei     = (const int*)  d_in[1];
    const float* wts    = (const float*)d_in[2];
    const int*   batch  = (const int*)  d_in[3];
    const int*   cnodes = (const int*)  d_in[4];
    const int*   cclus  = (const int*)  d_in[5];
    const int*   cbatch = (const int*)  d_in[6];
    const float* Win    = (const float*)d_in[7];
    const float* bin    = (const float*)d_in[8];
    const float* Wblk   = (const float*)d_in[9];
    const float* bblk   = (const float*)d_in[10];
    const float* gma    = (const float*)d_in[11];
    const float* bta    = (const float*)d_in[12];
    const float* bmean  = (const float*)d_in[13];
    const float* bvar   = (const float*)d_in[14];
    const float* W1     = (const float*)d_in[15];
    const float* b1     = (const float*)d_in[16];
    const float* W2     = (const float*)d_in[17];
    const float* b2     = (const float*)d_in[18];
    float* out = (float*)d_out;

    const int N  = in_sizes[0] / H;
    const int E  = in_sizes[1] / 2;
    const int M  = in_sizes[4];
    const int KC = in_sizes[6];
    const int Bq = out_size / 10;

    const int* src = ei;
    const int* dst = ei + E;

    const long NH = (long)N * H;
    const long KH = (long)KC * H;

    // ---- workspace layout (floats/ints, all region starts even) ----
    float* ws   = (float*)d_ws;
    float* A    = ws;                 // xw, later zn            [NH]
    float* Bb   = A + NH;             // h, later ye             [NH]
    float* C    = Bb + NH;            // x_add -> xws (in-place) [KH]
    float* D    = C + KH;             // x_max -> hp             [KH]
    float* dinv = D + KH;             //                         [N]
    float* ye1  = dinv + N;           //                         [N]
    float* dinvp= ye1 + N;            //                         [KC]
    float* z    = dinvp + KC;         // pooled features         [Bq*512]
    float* cc   = z + (long)Bq * 512; // cluster counts          [Bq]
    int* ieoffs = (int*)(cc + Bq);    // edge CSR offsets (dst)  [N]
    int* ipoffs = ieoffs + N;         // pair CSR by cluster     [KC]
    int* iqoffs = ipoffs + KC;        // pair CSR by node        [N]
    int* epack  = iqoffs + N;         // {src, w} per edge slot  [2E]
    int* pslots = epack + 2L * E;     // node per cluster-slot   [M]
    int* qslots = pslots + M;         // cluster per node-slot   [M]
    int* spart  = qslots + M;         // scan partials           [2048]

    // ---- 1. build CSRs ----
    hipMemsetAsync(ieoffs, 0, (2L * N + KC) * sizeof(int), stream);
    count_kernel<<<(E + 255) / 256, 256, 0, stream>>>(dst, ieoffs, E);
    count_kernel<<<(M + 255) / 256, 256, 0, stream>>>(cclus, ipoffs, M);
    count_kernel<<<(M + 255) / 256, 256, 0, stream>>>(cnodes, iqoffs, M);
    scan_ex(ieoffs, N, spart, stream);
    scan_ex(ipoffs, KC, spart, stream);
    scan_ex(iqoffs, N, spart, stream);
    fill_edges<<<(E + 255) / 256, 256, 0, stream>>>(src, dst, wts, ieoffs, epack, E);
    fill_pairs<<<(M + 255) / 256, 256, 0, stream>>>(cclus, cnodes, ipoffs, pslots, M);
    fill_pairs<<<(M + 255) / 256, 256, 0, stream>>>(cnodes, cclus, iqoffs, qslots, M);

    // ---- 2. scalar reductions: dinv, ye1, dinvp ----
    node_scalars<<<(N + 255) / 256, 256, 0, stream>>>(ieoffs, epack, iqoffs, dinv, ye1, N);
    cluster_dinvp<<<(KC + 255) / 256, 256, 0, stream>>>(ipoffs, pslots, ye1, dinvp, KC);

    // ---- 3. conv_in (fused): xw = x@Win, then gather+relu ----
    gemm128<<<(N + 63) / 64, 256, 0, stream>>>(x, Win, A, N, nullptr, 0);
    gcn1_gather<<<(N + 3) / 4, 256, 0, stream>>>(ieoffs, epack, dinv, A, bin, Bb, N);

    // ---- 4. pools of h ----
    hipMemsetAsync(z, 0, ((long)Bq * 512 + Bq) * sizeof(float), stream);
    cover_pool<<<(KC + 3) / 4, 256, 0, stream>>>(ipoffs, pslots, Bb, C, D, KC);
    seg_pool<<<1024, 128, 0, stream>>>(Bb, batch, z, N, 0, 128);
    hist64<<<256, 256, 0, stream>>>(cbatch, cc, KC);

    // ---- 5. xws = dinvp * (x_add@Wtop + x_max@Wbot), in place over C ----
    gemm128<<<(KC + 63) / 64, 256, 0, stream>>>(C, Wblk, C, KC, nullptr, 0);
    gemm128<<<(KC + 63) / 64, 256, 0, stream>>>(D, Wblk + 128 * 128, C, KC, dinvp, 1);

    // ---- 6. aprime(xws) + hp, all gathers ----
    zn_gather<<<(N + 3) / 4, 256, 0, stream>>>(iqoffs, qslots, C, A, N);       // A = zn
    edge_gather_plain<<<(N + 3) / 4, 256, 0, stream>>>(ieoffs, epack, A, Bb, N); // Bb = ye
    aphp_gather<<<(KC + 3) / 4, 256, 0, stream>>>(ipoffs, pslots, Bb, C, dinvp, bblk, D, KC); // D = hp

    // ---- 7. cluster pools of hp + head ----
    seg_pool<<<512, 128, 0, stream>>>(D, cbatch, z, KC, 256, 384);
    head_kernel<<<Bq, 128, 0, stream>>>(z, cc, gma, bta, bmean, bvar, W1, b1, W2, b2, out);
}

// Round 6
// 723.018 us; speedup vs baseline: 9.4319x; 1.1930x over previous
//
#include <hip/hip_runtime.h>

// ---------------------------------------------------------------------------
// KPlexPool: GCN -> pools -> matrix-free pooled GCN -> MLP head + softmax
// Sizes: N=100000, E=1600000, H=128, M=150000, KC=60000, B=64, C_OUT=10
// Round 4: scatter-atomics -> device-built CSR gathers.
// Round 5: bf16 storage for gather-heavy intermediates (xw, zn, xws) --
//          halves the two 819MB-logical edge gathers; 2-edges-per-wave
//          half-wave structure in the edge gathers (more bytes in flight).
//          fp32 accumulation everywhere; h/ye/pools stay fp32.
// ---------------------------------------------------------------------------

#define H 128

__device__ __forceinline__ void atomAddF(float* p, float v) {
    unsafeAtomicAdd(p, v);   // global_atomic_add_f32 on gfx950
}
__device__ __forceinline__ void atomMaxPos(float* p, float v) {
    // valid for non-negative floats (bit pattern order == numeric order)
    atomicMax(reinterpret_cast<int*>(p), __float_as_int(v));
}

// bf16 helpers: RNE pack, shift unpack
__device__ __forceinline__ unsigned int bfr(float f) {
    unsigned int u = __float_as_uint(f);
    return (u + 0x7fffu + ((u >> 16) & 1u)) >> 16;
}
__device__ __forceinline__ unsigned int pk2(float lo, float hi) {
    return bfr(lo) | (bfr(hi) << 16);
}
__device__ __forceinline__ float unlo(unsigned int v) { return __uint_as_float(v << 16); }
__device__ __forceinline__ float unhi(unsigned int v) { return __uint_as_float(v & 0xffff0000u); }

// ========================= CSR build =======================================
__global__ void count_kernel(const int* __restrict__ key, int* __restrict__ cnt, int n) {
    int i = blockIdx.x * blockDim.x + threadIdx.x;
    if (i < n) atomicAdd(&cnt[key[i]], 1);
}
__global__ void count_pairs(const int* __restrict__ a, const int* __restrict__ b,
                            int* __restrict__ ca, int* __restrict__ cb, int M) {
    int i = blockIdx.x * blockDim.x + threadIdx.x;
    if (i < M) { atomicAdd(&ca[a[i]], 1); atomicAdd(&cb[b[i]], 1); }
}

// exclusive scan of c[0..m) in place, 1024 elems/block
__global__ __launch_bounds__(256) void scan_partial(const int* __restrict__ c,
                                                    int* __restrict__ part, int m) {
    __shared__ int red[4];
    int base = blockIdx.x * 1024, t = threadIdx.x;
    int s = 0;
    for (int j = t; j < 1024; j += 256) { int i = base + j; if (i < m) s += c[i]; }
    for (int o = 32; o; o >>= 1) s += __shfl_down(s, o, 64);
    if ((t & 63) == 0) red[t >> 6] = s;
    __syncthreads();
    if (t == 0) part[blockIdx.x] = red[0] + red[1] + red[2] + red[3];
}
__global__ void scan_spine(int* part, int G) {
    if (threadIdx.x == 0) {
        int acc = 0;
        for (int i = 0; i < G; ++i) { int v = part[i]; part[i] = acc; acc += v; }
    }
}
__global__ __launch_bounds__(256) void scan_apply(int* __restrict__ c,
                                                  const int* __restrict__ part, int m) {
    __shared__ int wsum[4];
    int base = blockIdx.x * 1024, t = threadIdx.x;
    int i0 = base + t * 4;
    int v0 = 0, v1 = 0, v2 = 0, v3 = 0;
    if (i0     < m) v0 = c[i0];
    if (i0 + 1 < m) v1 = c[i0 + 1];
    if (i0 + 2 < m) v2 = c[i0 + 2];
    if (i0 + 3 < m) v3 = c[i0 + 3];
    int ts = v0 + v1 + v2 + v3;
    int lane = t & 63, w = t >> 6;
    int sc = ts;
    for (int o = 1; o < 64; o <<= 1) { int u = __shfl_up(sc, o, 64); if (lane >= o) sc += u; }
    if (lane == 63) wsum[w] = sc;
    __syncthreads();
    int off = part[blockIdx.x];
    for (int k = 0; k < w; ++k) off += wsum[k];
    int ex = off + sc - ts;
    if (i0     < m) c[i0]     = ex;
    if (i0 + 1 < m) c[i0 + 1] = ex + v0;
    if (i0 + 2 < m) c[i0 + 2] = ex + v0 + v1;
    if (i0 + 3 < m) c[i0 + 3] = ex + v0 + v1 + v2;
}

// fill: after this, offs[i] = end of bucket i; row i = [i?offs[i-1]:0, offs[i])
__global__ void fill_edges(const int* __restrict__ src, const int* __restrict__ dst,
                           const float* __restrict__ w, int* __restrict__ offs,
                           int* __restrict__ pack, int E) {
    int e = blockIdx.x * blockDim.x + threadIdx.x;
    if (e >= E) return;
    int pos = atomicAdd(&offs[dst[e]], 1);
    ((int2*)pack)[pos] = make_int2(src[e], __float_as_int(w[e]));
}
__global__ void fill_pairs(const int* __restrict__ key, const int* __restrict__ val,
                           int* __restrict__ offs, int* __restrict__ slots, int M) {
    int p = blockIdx.x * blockDim.x + threadIdx.x;
    if (p >= M) return;
    int pos = atomicAdd(&offs[key[p]], 1);
    slots[pos] = val[p];
}

// ========================= scalar CSR reductions ===========================
// dinv[n] = rsqrt(sum_e w + 1);  ye1[n] = sum_e w * paircount[src]
__global__ void node_scalars(const int* __restrict__ eoffs, const int* __restrict__ epack,
                             const int* __restrict__ qoffs,
                             float* __restrict__ dinv, float* __restrict__ ye1, int N) {
    int n = blockIdx.x * blockDim.x + threadIdx.x;
    if (n >= N) return;
    int b = n ? eoffs[n - 1] : 0, e = eoffs[n];
    float dg = 0.f, y = 0.f;
    for (int i = b; i < e; ++i) {
        int2 pk = ((const int2*)epack)[i];
        float w = __int_as_float(pk.y);
        dg += w;
        int zc = qoffs[pk.x] - (pk.x ? qoffs[pk.x - 1] : 0);
        y += w * (float)zc;
    }
    dinv[n] = rsqrtf(dg + 1.0f);
    ye1[n] = y;
}
// dinvp[c] = rsqrt(sum_{p in cluster c} ye1[node_p] + 1)
__global__ void cluster_dinvp(const int* __restrict__ poffs, const int* __restrict__ pslots,
                              const float* __restrict__ ye1, float* __restrict__ dinvp, int KC) {
    int c = blockIdx.x * blockDim.x + threadIdx.x;
    if (c >= KC) return;
    int b = c ? poffs[c - 1] : 0, e = poffs[c];
    float s = 0.f;
    for (int i = b; i < e; ++i) s += ye1[pslots[i]];
    dinvp[c] = rsqrtf(s + 1.0f);
}

// ========================= GEMM K=128 ======================================
// 64 rows x 128 cols per block, 256 threads, thread = 4 rows x 8 cols.
// Acc: optional fp32 row-add source. Out is fp32 (Outf) or packed bf16 (Outb).
// NOTE: no __restrict__ on X/Outf -- called in-place (X==Outf); the
// __syncthreads() before writeback makes intra-block row sharing safe.
__global__ __launch_bounds__(256) void gemm128(
    const float* X, const float* __restrict__ W,
    float* Outf, unsigned int* __restrict__ Outb,
    const float* __restrict__ Acc, const float* __restrict__ rowscale, int nrows)
{
    __shared__ float Wl[128 * 128];
    int t = threadIdx.x;
    for (int i = t; i < 4096; i += 256)
        ((float4*)Wl)[i] = ((const float4*)W)[i];
    __syncthreads();

    int cgrp = t & 15;
    int rgrp = t >> 4;
    long rb = (long)blockIdx.x * 64 + rgrp * 4;
    long nm1 = (long)nrows - 1;
    const float* xr0 = X + (rb + 0 < nm1 ? rb + 0 : nm1) * H;
    const float* xr1 = X + (rb + 1 < nm1 ? rb + 1 : nm1) * H;
    const float* xr2 = X + (rb + 2 < nm1 ? rb + 2 : nm1) * H;
    const float* xr3 = X + (rb + 3 < nm1 ? rb + 3 : nm1) * H;

    float acc[4][8];
#pragma unroll
    for (int i = 0; i < 4; ++i)
#pragma unroll
        for (int j = 0; j < 8; ++j) acc[i][j] = 0.f;

    for (int k = 0; k < 128; ++k) {
        float4 w0 = ((float4*)Wl)[k * 32 + cgrp * 2];
        float4 w1 = ((float4*)Wl)[k * 32 + cgrp * 2 + 1];
        float xv0 = xr0[k], xv1 = xr1[k], xv2 = xr2[k], xv3 = xr3[k];
        acc[0][0] += xv0 * w0.x; acc[0][1] += xv0 * w0.y; acc[0][2] += xv0 * w0.z; acc[0][3] += xv0 * w0.w;
        acc[0][4] += xv0 * w1.x; acc[0][5] += xv0 * w1.y; acc[0][6] += xv0 * w1.z; acc[0][7] += xv0 * w1.w;
        acc[1][0] += xv1 * w0.x; acc[1][1] += xv1 * w0.y; acc[1][2] += xv1 * w0.z; acc[1][3] += xv1 * w0.w;
        acc[1][4] += xv1 * w1.x; acc[1][5] += xv1 * w1.y; acc[1][6] += xv1 * w1.z; acc[1][7] += xv1 * w1.w;
        acc[2][0] += xv2 * w0.x; acc[2][1] += xv2 * w0.y; acc[2][2] += xv2 * w0.z; acc[2][3] += xv2 * w0.w;
        acc[2][4] += xv2 * w1.x; acc[2][5] += xv2 * w1.y; acc[2][6] += xv2 * w1.z; acc[2][7] += xv2 * w1.w;
        acc[3][0] += xv3 * w0.x; acc[3][1] += xv3 * w0.y; acc[3][2] += xv3 * w0.z; acc[3][3] += xv3 * w0.w;
        acc[3][4] += xv3 * w1.x; acc[3][5] += xv3 * w1.y; acc[3][6] += xv3 * w1.z; acc[3][7] += xv3 * w1.w;
    }

    __syncthreads();   // in-place safety: all reads of X complete before any write

#pragma unroll
    for (int i = 0; i < 4; ++i) {
        long gr = rb + i;
        if (gr >= nrows) continue;
        float4 o0 = make_float4(acc[i][0], acc[i][1], acc[i][2], acc[i][3]);
        float4 o1 = make_float4(acc[i][4], acc[i][5], acc[i][6], acc[i][7]);
        if (Acc) {
            const float* a = Acc + gr * H + cgrp * 8;
            float4 p0 = ((const float4*)a)[0], p1 = ((const float4*)a)[1];
            o0.x += p0.x; o0.y += p0.y; o0.z += p0.z; o0.w += p0.w;
            o1.x += p1.x; o1.y += p1.y; o1.z += p1.z; o1.w += p1.w;
        }
        if (rowscale) {
            float s = rowscale[gr];
            o0.x *= s; o0.y *= s; o0.z *= s; o0.w *= s;
            o1.x *= s; o1.y *= s; o1.z *= s; o1.w *= s;
        }
        if (Outb) {
            uint4 wv;
            wv.x = pk2(o0.x, o0.y); wv.y = pk2(o0.z, o0.w);
            wv.z = pk2(o1.x, o1.y); wv.w = pk2(o1.z, o1.w);
            ((uint4*)Outb)[gr * 16 + cgrp] = wv;
        } else {
            float* o = Outf + gr * H + cgrp * 8;
            ((float4*)o)[0] = o0;
            ((float4*)o)[1] = o1;
        }
    }
}

// ========================= vector CSR gathers ==============================
// GCN pass 1, fused: h[n] = relu(dinv_n*(sum w*dinv_s*xw[s] + dinv_n*xw[n]) + b)
// one wave per node; two 32-lane halves each handle one edge per iteration
// (bf16 row = 256B = 32 lanes x 8B). Halves combined via shfl_xor(32).
__global__ __launch_bounds__(256) void gcn1_gather(
    const int* __restrict__ eoffs, const int* __restrict__ epack,
    const float* __restrict__ dinv, const unsigned int* __restrict__ xwb,
    const float* __restrict__ bin, float* __restrict__ h, int N)
{
    int n = blockIdx.x * 4 + (threadIdx.x >> 6);
    if (n >= N) return;
    int lane = threadIdx.x & 63;
    int cl = lane & 31, half = lane >> 5;
    int b = n ? eoffs[n - 1] : 0, e = eoffs[n];
    const uint2* X = (const uint2*)xwb;
    float4 acc = make_float4(0.f, 0.f, 0.f, 0.f);
    for (int i = b; i < e; i += 64) {
        int cnt = min(64, e - i);
        int s_l = 0; float sc_l = 0.f;
        if (lane < cnt) {
            int2 pk = ((const int2*)epack)[i + lane];
            s_l = pk.x;
            sc_l = __int_as_float(pk.y) * dinv[pk.x];
        }
        int steps = (cnt + 1) >> 1;
        for (int j = 0; j < steps; ++j) {
            int idx = 2 * j + half;              // sc==0 for idx>=cnt (odd tail)
            int s = __shfl(s_l, idx, 64);
            float sc = __shfl(sc_l, idx, 64);
            uint2 v = X[(long)s * 32 + cl];
            acc.x += sc * unlo(v.x); acc.y += sc * unhi(v.x);
            acc.z += sc * unlo(v.y); acc.w += sc * unhi(v.y);
        }
    }
    acc.x += __shfl_xor(acc.x, 32, 64);
    acc.y += __shfl_xor(acc.y, 32, 64);
    acc.z += __shfl_xor(acc.z, 32, 64);
    acc.w += __shfl_xor(acc.w, 32, 64);
    if (half == 0) {
        float dd = dinv[n];
        uint2 sv = X[(long)n * 32 + cl];
        float4 bb = ((const float4*)bin)[cl];
        float4 o;
        o.x = fmaxf(dd * (acc.x + dd * unlo(sv.x)) + bb.x, 0.f);
        o.y = fmaxf(dd * (acc.y + dd * unhi(sv.x)) + bb.y, 0.f);
        o.z = fmaxf(dd * (acc.z + dd * unlo(sv.y)) + bb.z, 0.f);
        o.w = fmaxf(dd * (acc.w + dd * unhi(sv.y)) + bb.w, 0.f);
        ((float4*)h)[(long)n * 32 + cl] = o;
    }
}

// plain edge gather from bf16 rows: Out[n] = sum_e w * X[src]  (fp32 out)
__global__ __launch_bounds__(256) void edge_gather_plain(
    const int* __restrict__ eoffs, const int* __restrict__ epack,
    const unsigned int* __restrict__ Xb, float* __restrict__ Out, int N)
{
    int n = blockIdx.x * 4 + (threadIdx.x >> 6);
    if (n >= N) return;
    int lane = threadIdx.x & 63;
    int cl = lane & 31, half = lane >> 5;
    int b = n ? eoffs[n - 1] : 0, e = eoffs[n];
    const uint2* X = (const uint2*)Xb;
    float4 acc = make_float4(0.f, 0.f, 0.f, 0.f);
    for (int i = b; i < e; i += 64) {
        int cnt = min(64, e - i);
        int s_l = 0; float sc_l = 0.f;
        if (lane < cnt) {
            int2 pk = ((const int2*)epack)[i + lane];
            s_l = pk.x; sc_l = __int_as_float(pk.y);
        }
        int steps = (cnt + 1) >> 1;
        for (int j = 0; j < steps; ++j) {
            int idx = 2 * j + half;
            int s = __shfl(s_l, idx, 64);
            float sc = __shfl(sc_l, idx, 64);
            uint2 v = X[(long)s * 32 + cl];
            acc.x += sc * unlo(v.x); acc.y += sc * unhi(v.x);
            acc.z += sc * unlo(v.y); acc.w += sc * unhi(v.y);
        }
    }
    acc.x += __shfl_xor(acc.x, 32, 64);
    acc.y += __shfl_xor(acc.y, 32, 64);
    acc.z += __shfl_xor(acc.z, 32, 64);
    acc.w += __shfl_xor(acc.w, 32, 64);
    if (half == 0)
        ((float4*)Out)[(long)n * 32 + cl] = acc;
}

// cover pool: x_add[c] = sum h[node], x_max[c] = max h[node]  (h >= 0, fp32)
// half-wave (32 lanes, float4) per cluster, 8 clusters per 256-block
__global__ __launch_bounds__(256) void cover_pool(
    const int* __restrict__ poffs, const int* __restrict__ pslots,
    const float* __restrict__ h, float* __restrict__ xadd,
    float* __restrict__ xmax, int KC)
{
    int c = blockIdx.x * 8 + (threadIdx.x >> 5);
    if (c >= KC) return;
    int cl = threadIdx.x & 31;
    int b = c ? poffs[c - 1] : 0, e = poffs[c];
    const float4* H4 = (const float4*)h;
    float4 s = make_float4(0.f, 0.f, 0.f, 0.f), m = s;
    for (int i = b; i < e; ++i) {
        int nd = pslots[i];
        float4 v = H4[(long)nd * 32 + cl];
        s.x += v.x; s.y += v.y; s.z += v.z; s.w += v.w;
        m.x = fmaxf(m.x, v.x); m.y = fmaxf(m.y, v.y);
        m.z = fmaxf(m.z, v.z); m.w = fmaxf(m.w, v.w);
    }
    ((float4*)xadd)[(long)c * 32 + cl] = s;
    ((float4*)xmax)[(long)c * 32 + cl] = m;
}

// zn[n] = sum_{p at node n} xws[cluster_p]   (bf16 in, bf16 out, fp32 accum)
__global__ __launch_bounds__(256) void zn_gather(
    const int* __restrict__ qoffs, const int* __restrict__ qslots,
    const unsigned int* __restrict__ xwsb, unsigned int* __restrict__ znb, int N)
{
    int n = blockIdx.x * 8 + (threadIdx.x >> 5);
    if (n >= N) return;
    int cl = threadIdx.x & 31;
    int b = n ? qoffs[n - 1] : 0, e = qoffs[n];
    const uint2* X = (const uint2*)xwsb;
    float4 a = make_float4(0.f, 0.f, 0.f, 0.f);
    for (int i = b; i < e; ++i) {
        int c = qslots[i];
        uint2 v = X[(long)c * 32 + cl];
        a.x += unlo(v.x); a.y += unhi(v.x);
        a.z += unlo(v.y); a.w += unhi(v.y);
    }
    ((uint2*)znb)[(long)n * 32 + cl] = make_uint2(pk2(a.x, a.y), pk2(a.z, a.w));
}

// hp[c] = relu(dinvp_c * (sum_{p in c} ye[node_p] + xws[c]) + b_blk)
__global__ __launch_bounds__(256) void aphp_gather(
    const int* __restrict__ poffs, const int* __restrict__ pslots,
    const float* __restrict__ ye, const unsigned int* __restrict__ xwsb,
    const float* __restrict__ dinvp, const float* __restrict__ bblk,
    float* __restrict__ hp, int KC)
{
    int c = blockIdx.x * 8 + (threadIdx.x >> 5);
    if (c >= KC) return;
    int cl = threadIdx.x & 31;
    int b = c ? poffs[c - 1] : 0, e = poffs[c];
    const float4* Y4 = (const float4*)ye;
    float4 a = make_float4(0.f, 0.f, 0.f, 0.f);
    for (int i = b; i < e; ++i) {
        int nd = pslots[i];
        float4 v = Y4[(long)nd * 32 + cl];
        a.x += v.x; a.y += v.y; a.z += v.z; a.w += v.w;
    }
    float d = dinvp[c];
    uint2 xv = ((const uint2*)xwsb)[(long)c * 32 + cl];
    float4 bb = ((const float4*)bblk)[cl];
    float4 o;
    o.x = fmaxf(d * (a.x + unlo(xv.x)) + bb.x, 0.f);
    o.y = fmaxf(d * (a.y + unhi(xv.x)) + bb.y, 0.f);
    o.z = fmaxf(d * (a.z + unlo(xv.y)) + bb.z, 0.f);
    o.w = fmaxf(d * (a.w + unhi(xv.y)) + bb.w, 0.f);
    ((float4*)hp)[(long)c * 32 + cl] = o;
}

// ========================= batch pools + head ==============================
__global__ __launch_bounds__(128) void seg_pool(
    const float* __restrict__ X, const int* __restrict__ seg,
    float* __restrict__ Z, int n, int sumoff, int maxoff)
{
    int j = threadIdx.x;
    long beg = (long)blockIdx.x * n / gridDim.x;
    long end = (long)(blockIdx.x + 1) * n / gridDim.x;
    if (beg >= end) return;
    int curb = seg[beg];
    float s = 0.f, mx = 0.f;
    for (long i = beg; i < end; ++i) {
        int b = seg[i];
        if (b != curb) {
            atomAddF(&Z[(long)curb * 512 + sumoff + j], s);
            atomMaxPos(&Z[(long)curb * 512 + maxoff + j], mx);
            s = 0.f; mx = 0.f; curb = b;
        }
        float v = X[i * (long)H + j];
        s += v; mx = fmaxf(mx, v);
    }
    atomAddF(&Z[(long)curb * 512 + sumoff + j], s);
    atomMaxPos(&Z[(long)curb * 512 + maxoff + j], mx);
}

__global__ void hist64(const int* __restrict__ seg, float* __restrict__ cc, int n) {
    __shared__ int hc[128];
    if (threadIdx.x < 128) hc[threadIdx.x] = 0;
    __syncthreads();
    for (int i = blockIdx.x * blockDim.x + threadIdx.x; i < n; i += gridDim.x * blockDim.x)
        atomicAdd(&hc[seg[i]], 1);
    __syncthreads();
    if (threadIdx.x < 128 && hc[threadIdx.x] != 0)
        atomAddF(&cc[threadIdx.x], (float)hc[threadIdx.x]);
}

__global__ __launch_bounds__(128) void head_kernel(
    const float* __restrict__ z, const float* __restrict__ cc,
    const float* __restrict__ gamma, const float* __restrict__ beta,
    const float* __restrict__ bmean, const float* __restrict__ bvar,
    const float* __restrict__ W1, const float* __restrict__ b1,
    const float* __restrict__ W2, const float* __restrict__ b2,
    float* __restrict__ out)
{
    __shared__ float zb[512];
    __shared__ float z1[128];
    __shared__ float lg[10];
    __shared__ float red[2];
    int b = blockIdx.x, t = threadIdx.x;
    float ccb = cc[b];
    for (int k = t; k < 512; k += 128) {
        float v = z[(long)b * 512 + k];
        if (k >= 256 && k < 384) v /= ccb;
        v = (v - bmean[k]) * rsqrtf(bvar[k] + 1e-5f) * gamma[k] + beta[k];
        zb[k] = v;
    }
    __syncthreads();
    float acc = b1[t];
    for (int k = 0; k < 512; ++k) acc += zb[k] * W1[k * 128 + t];
    z1[t] = fmaxf(acc, 0.f);
    __syncthreads();
    if (t < 10) {
        float a = b2[t];
        for (int k = 0; k < 128; ++k) a += z1[k] * W2[k * 10 + t];
        lg[t] = a;
    }
    __syncthreads();
    if (t == 0) {
        float m = lg[0];
        for (int i = 1; i < 10; ++i) m = fmaxf(m, lg[i]);
        float s = 0.f;
        for (int i = 0; i < 10; ++i) s += expf(lg[i] - m);
        red[0] = m; red[1] = s;
    }
    __syncthreads();
    if (t < 10) out[(long)b * 10 + t] = expf(lg[t] - red[0]) / red[1];
}

// ---------------------------------------------------------------------------
static void scan_ex(int* buf, int m, int* part, hipStream_t s) {
    int G = (m + 1023) / 1024;
    scan_partial<<<G, 256, 0, s>>>(buf, part, m);
    scan_spine<<<1, 64, 0, s>>>(part, G);
    scan_apply<<<G, 256, 0, s>>>(buf, part, m);
}

extern "C" void kernel_launch(void* const* d_in, const int* in_sizes, int n_in,
                              void* d_out, int out_size, void* d_ws, size_t ws_size,
                              hipStream_t stream)
{
    const float* x      = (const float*)d_in[0];
    const int*   ei     = (const int*)  d_in[1];
    const float* wts    = (const float*)d_in[2];
    const int*   batch  = (const int*)  d_in[3];
    const int*   cnodes = (const int*)  d_in[4];
    const int*   cclus  = (const int*)  d_in[5];
    const int*   cbatch = (const int*)  d_in[6];
    const float* Win    = (const float*)d_in[7];
    const float* bin    = (const float*)d_in[8];
    const float* Wblk   = (const float*)d_in[9];
    const float* bblk   = (const float*)d_in[10];
    const float* gma    = (const float*)d_in[11];
    const float* bta    = (const float*)d_in[12];
    const float* bmean  = (const float*)d_in[13];
    const float* bvar   = (const float*)d_in[14];
    const float* W1     = (const float*)d_in[15];
    const float* b1     = (const float*)d_in[16];
    const float* W2     = (const float*)d_in[17];
    const float* b2     = (const float*)d_in[18];
    float* out = (float*)d_out;

    const int N  = in_sizes[0] / H;
    const int E  = in_sizes[1] / 2;
    const int M  = in_sizes[4];
    const int KC = in_sizes[6];
    const int Bq = out_size / 10;

    const int* src = ei;
    const int* dst = ei + E;

    const long NH = (long)N * H;
    const long KH = (long)KC * H;

    // ---- workspace layout ----
    float* ws   = (float*)d_ws;
    float* Bb   = ws;                 // h, later ye             [NH] fp32
    float* C    = Bb + NH;            // x_add -> xws-fp32 tmp   [KH] fp32
    float* D    = C + KH;             // x_max -> hp             [KH] fp32
    float* dinv = D + KH;             //                         [N]
    float* ye1  = dinv + N;           //                         [N]
    float* dinvp= ye1 + N;            //                         [KC]
    float* z    = dinvp + KC;         // pooled features         [Bq*512]
    float* cc   = z + (long)Bq * 512; // cluster counts          [Bq]
    unsigned int* Abf = (unsigned int*)(cc + Bq);  // xw/zn bf16 [NH/2 uints]
    unsigned int* Cbf = Abf + NH / 2;              // xws bf16   [KH/2 uints]
    int* ieoffs = (int*)(Cbf + KH / 2); // edge CSR offsets (dst) [N]
    int* ipoffs = ieoffs + N;         // pair CSR by cluster     [KC]
    int* iqoffs = ipoffs + KC;        // pair CSR by node        [N]
    int* epack  = iqoffs + N;         // {src, w} per edge slot  [2E]
    int* pslots = epack + 2L * E;     // node per cluster-slot   [M]
    int* qslots = pslots + M;         // cluster per node-slot   [M]
    int* spart  = qslots + M;         // scan partials           [2048]

    // ---- 1. build CSRs ----
    hipMemsetAsync(ieoffs, 0, (2L * N + KC) * sizeof(int), stream);
    count_kernel<<<(E + 255) / 256, 256, 0, stream>>>(dst, ieoffs, E);
    count_pairs<<<(M + 255) / 256, 256, 0, stream>>>(cclus, cnodes, ipoffs, iqoffs, M);
    scan_ex(ieoffs, N, spart, stream);
    scan_ex(ipoffs, KC, spart, stream);
    scan_ex(iqoffs, N, spart, stream);
    fill_edges<<<(E + 255) / 256, 256, 0, stream>>>(src, dst, wts, ieoffs, epack, E);
    fill_pairs<<<(M + 255) / 256, 256, 0, stream>>>(cclus, cnodes, ipoffs, pslots, M);
    fill_pairs<<<(M + 255) / 256, 256, 0, stream>>>(cnodes, cclus, iqoffs, qslots, M);

    // ---- 2. scalar reductions: dinv, ye1, dinvp ----
    node_scalars<<<(N + 255) / 256, 256, 0, stream>>>(ieoffs, epack, iqoffs, dinv, ye1, N);
    cluster_dinvp<<<(KC + 255) / 256, 256, 0, stream>>>(ipoffs, pslots, ye1, dinvp, KC);

    // ---- 3. conv_in (fused): xw = x@Win (bf16), gather+relu -> h fp32 ----
    gemm128<<<(N + 63) / 64, 256, 0, stream>>>(x, Win, nullptr, Abf, nullptr, nullptr, N);
    gcn1_gather<<<(N + 3) / 4, 256, 0, stream>>>(ieoffs, epack, dinv, Abf, bin, Bb, N);

    // ---- 4. pools of h ----
    hipMemsetAsync(z, 0, ((long)Bq * 512 + Bq) * sizeof(float), stream);
    cover_pool<<<(KC + 7) / 8, 256, 0, stream>>>(ipoffs, pslots, Bb, C, D, KC);
    seg_pool<<<1024, 128, 0, stream>>>(Bb, batch, z, N, 0, 128);
    hist64<<<256, 256, 0, stream>>>(cbatch, cc, KC);

    // ---- 5. xws = dinvp * (x_add@Wtop + x_max@Wbot) -> bf16 Cbf ----
    gemm128<<<(KC + 63) / 64, 256, 0, stream>>>(C, Wblk, C, nullptr, nullptr, nullptr, KC);     // in-place fp32
    gemm128<<<(KC + 63) / 64, 256, 0, stream>>>(D, Wblk + 128 * 128, nullptr, Cbf, C, dinvp, KC);

    // ---- 6. aprime(xws) + hp, all gathers (bf16 payloads) ----
    zn_gather<<<(N + 7) / 8, 256, 0, stream>>>(iqoffs, qslots, Cbf, Abf, N);        // Abf = zn bf16
    edge_gather_plain<<<(N + 3) / 4, 256, 0, stream>>>(ieoffs, epack, Abf, Bb, N);  // Bb = ye fp32
    aphp_gather<<<(KC + 7) / 8, 256, 0, stream>>>(ipoffs, pslots, Bb, Cbf, dinvp, bblk, D, KC); // D = hp

    // ---- 7. cluster pools of hp + head ----
    seg_pool<<<512, 128, 0, stream>>>(D, cbatch, z, KC, 256, 384);
    head_kernel<<<Bq, 128, 0, stream>>>(z, cc, gma, bta, bmean, bvar, W1, b1, W2, b2, out);
}

// Round 7
// 623.701 us; speedup vs baseline: 10.9338x; 1.1592x over previous
//
#include <hip/hip_runtime.h>

// ---------------------------------------------------------------------------
// KPlexPool: GCN -> pools -> matrix-free pooled GCN -> MLP head + softmax
// Sizes: N=100000, E=1600000, H=128, M=150000, KC=60000, B=64, C_OUT=10
// Round 4: scatter-atomics -> device-built CSR gathers.
// Round 5: bf16 payloads for gather-heavy intermediates (xw, zn, xws).
// Round 7: (a) fill_edges/fill_pairs: nontemporal streaming reads (stop L2
//          thrash of dirty scatter lines; WRITE_SIZE was 8x payload) + 2-way
//          ILP on the returning atomics. (b) all dense GEMMs -> bf16 MFMA
//          (16x16x32, fp32 accum) with W prepacked into per-lane fragment
//          order (conflict-free lane-contiguous ds_read_b128); the two KC
//          GEMMs fuse into one K=256 pass with rowscale.
// ---------------------------------------------------------------------------

#define H 128

typedef __attribute__((ext_vector_type(4))) float f32x4;
typedef __attribute__((ext_vector_type(8))) short bf16x8;

__device__ __forceinline__ void atomAddF(float* p, float v) {
    unsafeAtomicAdd(p, v);   // global_atomic_add_f32 on gfx950
}
__device__ __forceinline__ void atomMaxPos(float* p, float v) {
    // valid for non-negative floats (bit pattern order == numeric order)
    atomicMax(reinterpret_cast<int*>(p), __float_as_int(v));
}

// bf16 helpers: RNE pack, shift unpack
__device__ __forceinline__ unsigned int bfr(float f) {
    unsigned int u = __float_as_uint(f);
    return (u + 0x7fffu + ((u >> 16) & 1u)) >> 16;
}
__device__ __forceinline__ unsigned int pk2(float lo, float hi) {
    return bfr(lo) | (bfr(hi) << 16);
}
__device__ __forceinline__ float unlo(unsigned int v) { return __uint_as_float(v << 16); }
__device__ __forceinline__ float unhi(unsigned int v) { return __uint_as_float(v & 0xffff0000u); }

// ========================= CSR build =======================================
__global__ void count_kernel(const int* __restrict__ key, int* __restrict__ cnt, int n) {
    int i = blockIdx.x * blockDim.x + threadIdx.x;
    if (i < n) atomicAdd(&cnt[__builtin_nontemporal_load(key + i)], 1);
}
__global__ void count_pairs(const int* __restrict__ a, const int* __restrict__ b,
                            int* __restrict__ ca, int* __restrict__ cb, int M) {
    int i = blockIdx.x * blockDim.x + threadIdx.x;
    if (i < M) {
        atomicAdd(&ca[__builtin_nontemporal_load(a + i)], 1);
        atomicAdd(&cb[__builtin_nontemporal_load(b + i)], 1);
    }
}

// exclusive scan of c[0..m) in place, 1024 elems/block
__global__ __launch_bounds__(256) void scan_partial(const int* __restrict__ c,
                                                    int* __restrict__ part, int m) {
    __shared__ int red[4];
    int base = blockIdx.x * 1024, t = threadIdx.x;
    int s = 0;
    for (int j = t; j < 1024; j += 256) { int i = base + j; if (i < m) s += c[i]; }
    for (int o = 32; o; o >>= 1) s += __shfl_down(s, o, 64);
    if ((t & 63) == 0) red[t >> 6] = s;
    __syncthreads();
    if (t == 0) part[blockIdx.x] = red[0] + red[1] + red[2] + red[3];
}
__global__ void scan_spine(int* part, int G) {
    if (threadIdx.x == 0) {
        int acc = 0;
        for (int i = 0; i < G; ++i) { int v = part[i]; part[i] = acc; acc += v; }
    }
}
__global__ __launch_bounds__(256) void scan_apply(int* __restrict__ c,
                                                  const int* __restrict__ part, int m) {
    __shared__ int wsum[4];
    int base = blockIdx.x * 1024, t = threadIdx.x;
    int i0 = base + t * 4;
    int v0 = 0, v1 = 0, v2 = 0, v3 = 0;
    if (i0     < m) v0 = c[i0];
    if (i0 + 1 < m) v1 = c[i0 + 1];
    if (i0 + 2 < m) v2 = c[i0 + 2];
    if (i0 + 3 < m) v3 = c[i0 + 3];
    int ts = v0 + v1 + v2 + v3;
    int lane = t & 63, w = t >> 6;
    int sc = ts;
    for (int o = 1; o < 64; o <<= 1) { int u = __shfl_up(sc, o, 64); if (lane >= o) sc += u; }
    if (lane == 63) wsum[w] = sc;
    __syncthreads();
    int off = part[blockIdx.x];
    for (int k = 0; k < w; ++k) off += wsum[k];
    int ex = off + sc - ts;
    if (i0     < m) c[i0]     = ex;
    if (i0 + 1 < m) c[i0 + 1] = ex + v0;
    if (i0 + 2 < m) c[i0 + 2] = ex + v0 + v1;
    if (i0 + 3 < m) c[i0 + 3] = ex + v0 + v1 + v2;
}

// fill: after this, offs[i] = end of bucket i; row i = [i?offs[i-1]:0, offs[i])
// nt loads keep streaming reads from evicting dirty scatter lines out of L2;
// 2 edges/thread = 2 independent returning-atomic chains in flight.
__global__ void fill_edges(const int* __restrict__ src, const int* __restrict__ dst,
                           const float* __restrict__ w, int* __restrict__ offs,
                           int* __restrict__ pack, int E) {
    int i = blockIdx.x * blockDim.x + threadIdx.x;
    int e0 = i * 2, e1 = e0 + 1;
    if (e0 >= E) return;
    int  d0 = __builtin_nontemporal_load(dst + e0);
    int  s0 = __builtin_nontemporal_load(src + e0);
    float w0 = __builtin_nontemporal_load(w + e0);
    bool has1 = e1 < E;
    int d1 = d0, s1 = 0; float w1 = 0.f;
    if (has1) {
        d1 = __builtin_nontemporal_load(dst + e1);
        s1 = __builtin_nontemporal_load(src + e1);
        w1 = __builtin_nontemporal_load(w + e1);
    }
    int p0 = atomicAdd(&offs[d0], 1);
    int p1 = has1 ? atomicAdd(&offs[d1], 1) : 0;
    ((int2*)pack)[p0] = make_int2(s0, __float_as_int(w0));
    if (has1) ((int2*)pack)[p1] = make_int2(s1, __float_as_int(w1));
}
__global__ void fill_pairs(const int* __restrict__ key, const int* __restrict__ val,
                           int* __restrict__ offs, int* __restrict__ slots, int M) {
    int i = blockIdx.x * blockDim.x + threadIdx.x;
    int p0 = i * 2, p1 = p0 + 1;
    if (p0 >= M) return;
    int k0 = __builtin_nontemporal_load(key + p0);
    int v0 = __builtin_nontemporal_load(val + p0);
    bool has1 = p1 < M;
    int k1 = k0, v1 = 0;
    if (has1) {
        k1 = __builtin_nontemporal_load(key + p1);
        v1 = __builtin_nontemporal_load(val + p1);
    }
    int q0 = atomicAdd(&offs[k0], 1);
    int q1 = has1 ? atomicAdd(&offs[k1], 1) : 0;
    slots[q0] = v0;
    if (has1) slots[q1] = v1;
}

// ========================= scalar CSR reductions ===========================
// dinv[n] = rsqrt(sum_e w + 1);  ye1[n] = sum_e w * paircount[src]
__global__ void node_scalars(const int* __restrict__ eoffs, const int* __restrict__ epack,
                             const int* __restrict__ qoffs,
                             float* __restrict__ dinv, float* __restrict__ ye1, int N) {
    int n = blockIdx.x * blockDim.x + threadIdx.x;
    if (n >= N) return;
    int b = n ? eoffs[n - 1] : 0, e = eoffs[n];
    float dg = 0.f, y = 0.f;
    for (int i = b; i < e; ++i) {
        int2 pk = ((const int2*)epack)[i];
        float w = __int_as_float(pk.y);
        dg += w;
        int zc = qoffs[pk.x] - (pk.x ? qoffs[pk.x - 1] : 0);
        y += w * (float)zc;
    }
    dinv[n] = rsqrtf(dg + 1.0f);
    ye1[n] = y;
}
// dinvp[c] = rsqrt(sum_{p in cluster c} ye1[node_p] + 1)
__global__ void cluster_dinvp(const int* __restrict__ poffs, const int* __restrict__ pslots,
                              const float* __restrict__ ye1, float* __restrict__ dinvp, int KC) {
    int c = blockIdx.x * blockDim.x + threadIdx.x;
    if (c >= KC) return;
    int b = c ? poffs[c - 1] : 0, e = poffs[c];
    float s = 0.f;
    for (int i = b; i < e; ++i) s += ye1[pslots[i]];
    dinvp[c] = rsqrtf(s + 1.0f);
}

// ========================= MFMA GEMM (bf16 in, fp32 accum) =================
// prepack W (fp32, (KSTEPS*32) x 128 row-major) into per-lane B-fragment
// order for mfma_f32_16x16x32_bf16: frag (ct,kb), lane l holds
// B[k][col] with col = ct*16 + (l&15), k = kb*32 + (l>>4)*8 + j, j=0..7.
template <int KSTEPS>
__global__ void prepack_w(const float* __restrict__ W, uint4* __restrict__ wp) {
    int idx = blockIdx.x * blockDim.x + threadIdx.x;   // frag-lane id
    if (idx >= 8 * KSTEPS * 64) return;
    int l = idx & 63;
    int f = idx >> 6;                 // ct*KSTEPS + kb
    int kb = f % KSTEPS, ct = f / KSTEPS;
    int col = ct * 16 + (l & 15);
    int k0 = kb * 32 + (l >> 4) * 8;
    uint4 u;
    u.x = pk2(W[(k0 + 0) * 128 + col], W[(k0 + 1) * 128 + col]);
    u.y = pk2(W[(k0 + 2) * 128 + col], W[(k0 + 3) * 128 + col]);
    u.z = pk2(W[(k0 + 4) * 128 + col], W[(k0 + 5) * 128 + col]);
    u.w = pk2(W[(k0 + 6) * 128 + col], W[(k0 + 7) * 128 + col]);
    wp[idx] = u;
}

// Out[r][c] = rowscale[r] * sum_k [XA|XB][r][k] * W[k][c], bf16 out.
// 64 rows x 128 cols per block, 4 waves, wave = 16 rows x 128 cols.
// A read 32B/lane from global fp32, packed to bf16 in-register.
// W frags staged to LDS; frag read is lane-contiguous ds_read_b128.
template <int KSTEPS>
__global__ __launch_bounds__(256) void gemm_mfma(
    const float* __restrict__ XA, const float* __restrict__ XB,
    const uint4* __restrict__ wpack, const float* __restrict__ rowscale,
    unsigned short* __restrict__ outb, int nrows)
{
    __shared__ uint4 Wl[8 * KSTEPS * 64];
    int t = threadIdx.x;
    for (int i = t; i < 8 * KSTEPS * 64; i += 256) Wl[i] = wpack[i];
    __syncthreads();

    int l = t & 63, wv = t >> 6;
    int row0 = blockIdx.x * 64 + wv * 16;
    int rr = row0 + (l & 15);
    long rc = (rr < nrows ? rr : nrows - 1);
    int kq = (l >> 4) * 8;

    f32x4 acc[8];
#pragma unroll
    for (int ct = 0; ct < 8; ++ct) acc[ct] = (f32x4)0.f;

#pragma unroll
    for (int kb = 0; kb < KSTEPS; ++kb) {
        const float* s = (KSTEPS == 8 && kb >= 4) ? XB : XA;
        int kbb = (KSTEPS == 8) ? (kb & 3) : kb;
        const float* p = s + rc * 128 + kbb * 32 + kq;
        float4 a0 = ((const float4*)p)[0];
        float4 a1 = ((const float4*)p)[1];
        union { uint4 u; bf16x8 v; } af;
        af.u.x = pk2(a0.x, a0.y); af.u.y = pk2(a0.z, a0.w);
        af.u.z = pk2(a1.x, a1.y); af.u.w = pk2(a1.z, a1.w);
#pragma unroll
        for (int ct = 0; ct < 8; ++ct) {
            union { uint4 u; bf16x8 v; } bf;
            bf.u = Wl[(ct * KSTEPS + kb) * 64 + l];
            acc[ct] = __builtin_amdgcn_mfma_f32_16x16x32_bf16(af.v, bf.v, acc[ct], 0, 0, 0);
        }
    }

    // C/D: col = l&15 (+ct*16), row = row0 + (l>>4)*4 + reg   [m89-verified]
    int rbase = row0 + (l >> 4) * 4;
    float sc[4];
#pragma unroll
    for (int g = 0; g < 4; ++g)
        sc[g] = rowscale ? (rbase + g < nrows ? rowscale[rbase + g] : 1.f) : 1.f;
#pragma unroll
    for (int ct = 0; ct < 8; ++ct) {
        int col = ct * 16 + (l & 15);
#pragma unroll
        for (int g = 0; g < 4; ++g) {
            int r = rbase + g;
            if (r < nrows)
                outb[(long)r * 128 + col] = (unsigned short)bfr(acc[ct][g] * sc[g]);
        }
    }
}

// ========================= vector CSR gathers ==============================
// GCN pass 1, fused: h[n] = relu(dinv_n*(sum w*dinv_s*xw[s] + dinv_n*xw[n]) + b)
// one wave per node; two 32-lane halves each handle one edge per iteration
// (bf16 row = 256B = 32 lanes x 8B). Halves combined via shfl_xor(32).
__global__ __launch_bounds__(256) void gcn1_gather(
    const int* __restrict__ eoffs, const int* __restrict__ epack,
    const float* __restrict__ dinv, const unsigned int* __restrict__ xwb,
    const float* __restrict__ bin, float* __restrict__ h, int N)
{
    int n = blockIdx.x * 4 + (threadIdx.x >> 6);
    if (n >= N) return;
    int lane = threadIdx.x & 63;
    int cl = lane & 31, half = lane >> 5;
    int b = n ? eoffs[n - 1] : 0, e = eoffs[n];
    const uint2* X = (const uint2*)xwb;
    float4 acc = make_float4(0.f, 0.f, 0.f, 0.f);
    for (int i = b; i < e; i += 64) {
        int cnt = min(64, e - i);
        int s_l = 0; float sc_l = 0.f;
        if (lane < cnt) {
            int2 pk = ((const int2*)epack)[i + lane];
            s_l = pk.x;
            sc_l = __int_as_float(pk.y) * dinv[pk.x];
        }
        int steps = (cnt + 1) >> 1;
        for (int j = 0; j < steps; ++j) {
            int idx = 2 * j + half;              // sc==0 for idx>=cnt (odd tail)
            int s = __shfl(s_l, idx, 64);
            float sc = __shfl(sc_l, idx, 64);
            uint2 v = X[(long)s * 32 + cl];
            acc.x += sc * unlo(v.x); acc.y += sc * unhi(v.x);
            acc.z += sc * unlo(v.y); acc.w += sc * unhi(v.y);
        }
    }
    acc.x += __shfl_xor(acc.x, 32, 64);
    acc.y += __shfl_xor(acc.y, 32, 64);
    acc.z += __shfl_xor(acc.z, 32, 64);
    acc.w += __shfl_xor(acc.w, 32, 64);
    if (half == 0) {
        float dd = dinv[n];
        uint2 sv = X[(long)n * 32 + cl];
        float4 bb = ((const float4*)bin)[cl];
        float4 o;
        o.x = fmaxf(dd * (acc.x + dd * unlo(sv.x)) + bb.x, 0.f);
        o.y = fmaxf(dd * (acc.y + dd * unhi(sv.x)) + bb.y, 0.f);
        o.z = fmaxf(dd * (acc.z + dd * unlo(sv.y)) + bb.z, 0.f);
        o.w = fmaxf(dd * (acc.w + dd * unhi(sv.y)) + bb.w, 0.f);
        ((float4*)h)[(long)n * 32 + cl] = o;
    }
}

// plain edge gather from bf16 rows: Out[n] = sum_e w * X[src]  (fp32 out)
__global__ __launch_bounds__(256) void edge_gather_plain(
    const int* __restrict__ eoffs, const int* __restrict__ epack,
    const unsigned int* __restrict__ Xb, float* __restrict__ Out, int N)
{
    int n = blockIdx.x * 4 + (threadIdx.x >> 6);
    if (n >= N) return;
    int lane = threadIdx.x & 63;
    int cl = lane & 31, half = lane >> 5;
    int b = n ? eoffs[n - 1] : 0, e = eoffs[n];
    const uint2* X = (const uint2*)Xb;
    float4 acc = make_float4(0.f, 0.f, 0.f, 0.f);
    for (int i = b; i < e; i += 64) {
        int cnt = min(64, e - i);
        int s_l = 0; float sc_l = 0.f;
        if (lane < cnt) {
            int2 pk = ((const int2*)epack)[i + lane];
            s_l = pk.x; sc_l = __int_as_float(pk.y);
        }
        int steps = (cnt + 1) >> 1;
        for (int j = 0; j < steps; ++j) {
            int idx = 2 * j + half;
            int s = __shfl(s_l, idx, 64);
            float sc = __shfl(sc_l, idx, 64);
            uint2 v = X[(long)s * 32 + cl];
            acc.x += sc * unlo(v.x); acc.y += sc * unhi(v.x);
            acc.z += sc * unlo(v.y); acc.w += sc * unhi(v.y);
        }
    }
    acc.x += __shfl_xor(acc.x, 32, 64);
    acc.y += __shfl_xor(acc.y, 32, 64);
    acc.z += __shfl_xor(acc.z, 32, 64);
    acc.w += __shfl_xor(acc.w, 32, 64);
    if (half == 0)
        ((float4*)Out)[(long)n * 32 + cl] = acc;
}

// cover pool: x_add[c] = sum h[node], x_max[c] = max h[node]  (h >= 0, fp32)
__global__ __launch_bounds__(256) void cover_pool(
    const int* __restrict__ poffs, const int* __restrict__ pslots,
    const float* __restrict__ h, float* __restrict__ xadd,
    float* __restrict__ xmax, int KC)
{
    int c = blockIdx.x * 8 + (threadIdx.x >> 5);
    if (c >= KC) return;
    int cl = threadIdx.x & 31;
    int b = c ? poffs[c - 1] : 0, e = poffs[c];
    const float4* H4 = (const float4*)h;
    float4 s = make_float4(0.f, 0.f, 0.f, 0.f), m = s;
    for (int i = b; i < e; ++i) {
        int nd = pslots[i];
        float4 v = H4[(long)nd * 32 + cl];
        s.x += v.x; s.y += v.y; s.z += v.z; s.w += v.w;
        m.x = fmaxf(m.x, v.x); m.y = fmaxf(m.y, v.y);
        m.z = fmaxf(m.z, v.z); m.w = fmaxf(m.w, v.w);
    }
    ((float4*)xadd)[(long)c * 32 + cl] = s;
    ((float4*)xmax)[(long)c * 32 + cl] = m;
}

// zn[n] = sum_{p at node n} xws[cluster_p]   (bf16 in, bf16 out, fp32 accum)
__global__ __launch_bounds__(256) void zn_gather(
    const int* __restrict__ qoffs, const int* __restrict__ qslots,
    const unsigned int* __restrict__ xwsb, unsigned int* __restrict__ znb, int N)
{
    int n = blockIdx.x * 8 + (threadIdx.x >> 5);
    if (n >= N) return;
    int cl = threadIdx.x & 31;
    int b = n ? qoffs[n - 1] : 0, e = qoffs[n];
    const uint2* X = (const uint2*)xwsb;
    float4 a = make_float4(0.f, 0.f, 0.f, 0.f);
    for (int i = b; i < e; ++i) {
        int c = qslots[i];
        uint2 v = X[(long)c * 32 + cl];
        a.x += unlo(v.x); a.y += unhi(v.x);
        a.z += unlo(v.y); a.w += unhi(v.y);
    }
    ((uint2*)znb)[(long)n * 32 + cl] = make_uint2(pk2(a.x, a.y), pk2(a.z, a.w));
}

// hp[c] = relu(dinvp_c * (sum_{p in c} ye[node_p] + xws[c]) + b_blk)
__global__ __launch_bounds__(256) void aphp_gather(
    const int* __restrict__ poffs, const int* __restrict__ pslots,
    const float* __restrict__ ye, const unsigned int* __restrict__ xwsb,
    const float* __restrict__ dinvp, const float* __restrict__ bblk,
    float* __restrict__ hp, int KC)
{
    int c = blockIdx.x * 8 + (threadIdx.x >> 5);
    if (c >= KC) return;
    int cl = threadIdx.x & 31;
    int b = c ? poffs[c - 1] : 0, e = poffs[c];
    const float4* Y4 = (const float4*)ye;
    float4 a = make_float4(0.f, 0.f, 0.f, 0.f);
    for (int i = b; i < e; ++i) {
        int nd = pslots[i];
        float4 v = Y4[(long)nd * 32 + cl];
        a.x += v.x; a.y += v.y; a.z += v.z; a.w += v.w;
    }
    float d = dinvp[c];
    uint2 xv = ((const uint2*)xwsb)[(long)c * 32 + cl];
    float4 bb = ((const float4*)bblk)[cl];
    float4 o;
    o.x = fmaxf(d * (a.x + unlo(xv.x)) + bb.x, 0.f);
    o.y = fmaxf(d * (a.y + unhi(xv.x)) + bb.y, 0.f);
    o.z = fmaxf(d * (a.z + unlo(xv.y)) + bb.z, 0.f);
    o.w = fmaxf(d * (a.w + unhi(xv.y)) + bb.w, 0.f);
    ((float4*)hp)[(long)c * 32 + cl] = o;
}

// ========================= batch pools + head ==============================
__global__ __launch_bounds__(128) void seg_pool(
    const float* __restrict__ X, const int* __restrict__ seg,
    float* __restrict__ Z, int n, int sumoff, int maxoff)
{
    int j = threadIdx.x;
    long beg = (long)blockIdx.x * n / gridDim.x;
    long end = (long)(blockIdx.x + 1) * n / gridDim.x;
    if (beg >= end) return;
    int curb = seg[beg];
    float s = 0.f, mx = 0.f;
    for (long i = beg; i < end; ++i) {
        int b = seg[i];
        if (b != curb) {
            atomAddF(&Z[(long)curb * 512 + sumoff + j], s);
            atomMaxPos(&Z[(long)curb * 512 + maxoff + j], mx);
            s = 0.f; mx = 0.f; curb = b;
        }
        float v = X[i * (long)H + j];
        s += v; mx = fmaxf(mx, v);
    }
    atomAddF(&Z[(long)curb * 512 + sumoff + j], s);
    atomMaxPos(&Z[(long)curb * 512 + maxoff + j], mx);
}

__global__ void hist64(const int* __restrict__ seg, float* __restrict__ cc, int n) {
    __shared__ int hc[128];
    if (threadIdx.x < 128) hc[threadIdx.x] = 0;
    __syncthreads();
    for (int i = blockIdx.x * blockDim.x + threadIdx.x; i < n; i += gridDim.x * blockDim.x)
        atomicAdd(&hc[seg[i]], 1);
    __syncthreads();
    if (threadIdx.x < 128 && hc[threadIdx.x] != 0)
        atomAddF(&cc[threadIdx.x], (float)hc[threadIdx.x]);
}

__global__ __launch_bounds__(128) void head_kernel(
    const float* __restrict__ z, const float* __restrict__ cc,
    const float* __restrict__ gamma, const float* __restrict__ beta,
    const float* __restrict__ bmean, const float* __restrict__ bvar,
    const float* __restrict__ W1, const float* __restrict__ b1,
    const float* __restrict__ W2, const float* __restrict__ b2,
    float* __restrict__ out)
{
    __shared__ float zb[512];
    __shared__ float z1[128];
    __shared__ float lg[10];
    __shared__ float red[2];
    int b = blockIdx.x, t = threadIdx.x;
    float ccb = cc[b];
    for (int k = t; k < 512; k += 128) {
        float v = z[(long)b * 512 + k];
        if (k >= 256 && k < 384) v /= ccb;
        v = (v - bmean[k]) * rsqrtf(bvar[k] + 1e-5f) * gamma[k] + beta[k];
        zb[k] = v;
    }
    __syncthreads();
    float acc = b1[t];
    for (int k = 0; k < 512; ++k) acc += zb[k] * W1[k * 128 + t];
    z1[t] = fmaxf(acc, 0.f);
    __syncthreads();
    if (t < 10) {
        float a = b2[t];
        for (int k = 0; k < 128; ++k) a += z1[k] * W2[k * 10 + t];
        lg[t] = a;
    }
    __syncthreads();
    if (t == 0) {
        float m = lg[0];
        for (int i = 1; i < 10; ++i) m = fmaxf(m, lg[i]);
        float s = 0.f;
        for (int i = 0; i < 10; ++i) s += expf(lg[i] - m);
        red[0] = m; red[1] = s;
    }
    __syncthreads();
    if (t < 10) out[(long)b * 10 + t] = expf(lg[t] - red[0]) / red[1];
}

// ---------------------------------------------------------------------------
static void scan_ex(int* buf, int m, int* part, hipStream_t s) {
    int G = (m + 1023) / 1024;
    scan_partial<<<G, 256, 0, s>>>(buf, part, m);
    scan_spine<<<1, 64, 0, s>>>(part, G);
    scan_apply<<<G, 256, 0, s>>>(buf, part, m);
}

extern "C" void kernel_launch(void* const* d_in, const int* in_sizes, int n_in,
                              void* d_out, int out_size, void* d_ws, size_t ws_size,
                              hipStream_t stream)
{
    const float* x      = (const float*)d_in[0];
    const int*   ei     = (const int*)  d_in[1];
    const float* wts    = (const float*)d_in[2];
    const int*   batch  = (const int*)  d_in[3];
    const int*   cnodes = (const int*)  d_in[4];
    const int*   cclus  = (const int*)  d_in[5];
    const int*   cbatch = (const int*)  d_in[6];
    const float* Win    = (const float*)d_in[7];
    const float* bin    = (const float*)d_in[8];
    const float* Wblk   = (const float*)d_in[9];
    const float* bblk   = (const float*)d_in[10];
    const float* gma    = (const float*)d_in[11];
    const float* bta    = (const float*)d_in[12];
    const float* bmean  = (const float*)d_in[13];
    const float* bvar   = (const float*)d_in[14];
    const float* W1     = (const float*)d_in[15];
    const float* b1     = (const float*)d_in[16];
    const float* W2     = (const float*)d_in[17];
    const float* b2     = (const float*)d_in[18];
    float* out = (float*)d_out;

    const int N  = in_sizes[0] / H;
    const int E  = in_sizes[1] / 2;
    const int M  = in_sizes[4];
    const int KC = in_sizes[6];
    const int Bq = out_size / 10;

    const int* src = ei;
    const int* dst = ei + E;

    const long NH = (long)N * H;
    const long KH = (long)KC * H;

    // ---- workspace layout (wpack first for 16B alignment) ----
    float* ws    = (float*)d_ws;
    uint4* wpackN = (uint4*)ws;                     // 2048 uint4 (32KB)
    uint4* wpackK = wpackN + 2048;                  // 4096 uint4 (64KB)
    float* Bb   = (float*)(wpackK + 4096);          // h, later ye   [NH] fp32
    float* C    = Bb + NH;            // x_add                   [KH] fp32
    float* D    = C + KH;             // x_max -> hp             [KH] fp32
    float* dinv = D + KH;             //                         [N]
    float* ye1  = dinv + N;           //                         [N]
    float* dinvp= ye1 + N;            //                         [KC]
    float* z    = dinvp + KC;         // pooled features         [Bq*512]
    float* cc   = z + (long)Bq * 512; // cluster counts          [Bq]
    unsigned int* Abf = (unsigned int*)(cc + Bq);  // xw/zn bf16 [NH/2 uints]
    unsigned int* Cbf = Abf + NH / 2;              // xws bf16   [KH/2 uints]
    int* ieoffs = (int*)(Cbf + KH / 2); // edge CSR offsets (dst) [N]
    int* ipoffs = ieoffs + N;         // pair CSR by cluster     [KC]
    int* iqoffs = ipoffs + KC;        // pair CSR by node        [N]
    int* epack  = iqoffs + N;         // {src, w} per edge slot  [2E]
    int* pslots = epack + 2L * E;     // node per cluster-slot   [M]
    int* qslots = pslots + M;         // cluster per node-slot   [M]
    int* spart  = qslots + M;         // scan partials           [2048]

    // ---- 0. prepack weights into MFMA fragment order (bf16) ----
    prepack_w<4><<<8, 256, 0, stream>>>(Win, wpackN);
    prepack_w<8><<<16, 256, 0, stream>>>(Wblk, wpackK);

    // ---- 1. build CSRs ----
    hipMemsetAsync(ieoffs, 0, (2L * N + KC) * sizeof(int), stream);
    count_kernel<<<(E + 255) / 256, 256, 0, stream>>>(dst, ieoffs, E);
    count_pairs<<<(M + 255) / 256, 256, 0, stream>>>(cclus, cnodes, ipoffs, iqoffs, M);
    scan_ex(ieoffs, N, spart, stream);
    scan_ex(ipoffs, KC, spart, stream);
    scan_ex(iqoffs, N, spart, stream);
    fill_edges<<<(E / 2 + 256) / 256, 256, 0, stream>>>(src, dst, wts, ieoffs, epack, E);
    fill_pairs<<<(M / 2 + 256) / 256, 256, 0, stream>>>(cclus, cnodes, ipoffs, pslots, M);
    fill_pairs<<<(M / 2 + 256) / 256, 256, 0, stream>>>(cnodes, cclus, iqoffs, qslots, M);

    // ---- 2. scalar reductions: dinv, ye1, dinvp ----
    node_scalars<<<(N + 255) / 256, 256, 0, stream>>>(ieoffs, epack, iqoffs, dinv, ye1, N);
    cluster_dinvp<<<(KC + 255) / 256, 256, 0, stream>>>(ipoffs, pslots, ye1, dinvp, KC);

    // ---- 3. conv_in (fused): xw = x@Win (bf16 MFMA), gather+relu -> h ----
    gemm_mfma<4><<<(N + 63) / 64, 256, 0, stream>>>(x, nullptr, wpackN, nullptr,
                                                    (unsigned short*)Abf, N);
    gcn1_gather<<<(N + 3) / 4, 256, 0, stream>>>(ieoffs, epack, dinv, Abf, bin, Bb, N);

    // ---- 4. pools of h ----
    hipMemsetAsync(z, 0, ((long)Bq * 512 + Bq) * sizeof(float), stream);
    cover_pool<<<(KC + 7) / 8, 256, 0, stream>>>(ipoffs, pslots, Bb, C, D, KC);
    seg_pool<<<1024, 128, 0, stream>>>(Bb, batch, z, N, 0, 128);
    hist64<<<256, 256, 0, stream>>>(cbatch, cc, KC);

    // ---- 5. xws = dinvp * (x_add@Wtop + x_max@Wbot), one K=256 MFMA pass ----
    gemm_mfma<8><<<(KC + 63) / 64, 256, 0, stream>>>(C, D, wpackK, dinvp,
                                                     (unsigned short*)Cbf, KC);

    // ---- 6. aprime(xws) + hp, all gathers (bf16 payloads) ----
    zn_gather<<<(N + 7) / 8, 256, 0, stream>>>(iqoffs, qslots, Cbf, Abf, N);        // Abf = zn bf16
    edge_gather_plain<<<(N + 3) / 4, 256, 0, stream>>>(ieoffs, epack, Abf, Bb, N);  // Bb = ye fp32
    aphp_gather<<<(KC + 7) / 8, 256, 0, stream>>>(ipoffs, pslots, Bb, Cbf, dinvp, bblk, D, KC); // D = hp

    // ---- 7. cluster pools of hp + head ----
    seg_pool<<<512, 128, 0, stream>>>(D, cbatch, z, KC, 256, 384);
    head_kernel<<<Bq, 128, 0, stream>>>(z, cc, gma, bta, bmean, bvar, W1, b1, W2, b2, out);
}